// Round 6
// baseline (1733.756 us; speedup 1.0000x reference)
//
#include <hip/hip_runtime.h>
#include <cmath>

#define B_   128
#define N_   39
#define KNN_ 10
#define H_   256
#define K1_  32
#define K2_  26
#define K3_  21

static inline int cdiv(int a, int b) { return (a + b - 1) / b; }

typedef __attribute__((ext_vector_type(8))) short short8;
typedef __attribute__((ext_vector_type(4))) float floatx4;

__device__ inline short f2b(float f) {   // fp32 -> bf16 RNE
  unsigned u = __float_as_uint(f);
  u += 0x7fff + ((u >> 16) & 1);
  return (short)(u >> 16);
}
__device__ inline float b2f(short h) {
  return __uint_as_float(((unsigned)(unsigned short)h) << 16);
}
__device__ inline void f2b2(float v, short& hi, short& lo) {  // split: v ~= hi + lo
  hi = f2b(v);
  lo = f2b(v - b2f(hi));
}

// ---------- wave-wide argmax/argmin (64 lanes), ties -> lowest index ----------
__device__ inline void wave_argmax64(float& v, int& j) {
#pragma unroll
  for (int off = 32; off; off >>= 1) {
    float ov = __shfl_down(v, off, 64);
    int   oj = __shfl_down(j, off, 64);
    if (ov > v || (ov == v && oj < j)) { v = ov; j = oj; }
  }
  v = __shfl(v, 0, 64);
  j = __shfl(j, 0, 64);
}
__device__ inline void wave_argmin64(float& v, int& j) {
#pragma unroll
  for (int off = 32; off; off >>= 1) {
    float ov = __shfl_down(v, off, 64);
    int   oj = __shfl_down(j, off, 64);
    if (ov < v || (ov == v && oj < j)) { v = ov; j = oj; }
  }
  v = __shfl(v, 0, 64);
  j = __shfl(j, 0, 64);
}

// ---------------- one-shot weight prep + degree (7 tasks on blockIdx.y) ----------------
__global__ void prep_kernel(const float* __restrict__ w1, const float* __restrict__ w2,
                            const float* __restrict__ w3, const float* __restrict__ w6,
                            const float* __restrict__ l4, const float* __restrict__ l5,
                            const float* __restrict__ adj,
                            float* __restrict__ wcat1, float* __restrict__ wcat2,
                            float* __restrict__ wcat3,
                            short* __restrict__ w2h, short* __restrict__ w2l,
                            short* __restrict__ w3h, short* __restrict__ w3l,
                            short* __restrict__ w6h, short* __restrict__ w6l,
                            short* __restrict__ l4h, short* __restrict__ l4l,
                            short* __restrict__ l5h, short* __restrict__ l5l,
                            float* __restrict__ deg) {
  int task = blockIdx.y;
  int t = blockIdx.x * 256 + threadIdx.x;
  if (task == 0) {                        // wcat1 fp32 only (F=39, Hc=256)
    if (t >= 39 * 512) return;
    int k = t >> 9, c = t & 511;
    wcat1[t] = (c < 256) ? w1[k * 256 + c] - w1[(39 + k) * 256 + c]
                         : w1[(39 + k) * 256 + (c - 256)];
  } else if (task == 1) {                 // wcat2 fp32 + splitT (F=256, Hc=256)
    if (t >= 256 * 512) return;
    int k = t >> 9, c = t & 511;
    float v = (c < 256) ? w2[k * 256 + c] - w2[(256 + k) * 256 + c]
                        : w2[(256 + k) * 256 + (c - 256)];
    wcat2[t] = v;
    short hi, lo; f2b2(v, hi, lo);
    w2h[(size_t)c * 256 + k] = hi; w2l[(size_t)c * 256 + k] = lo;
  } else if (task == 2) {                 // wcat3 fp32 + splitT
    if (t >= 256 * 512) return;
    int k = t >> 9, c = t & 511;
    float v = (c < 256) ? w3[k * 256 + c] - w3[(256 + k) * 256 + c]
                        : w3[(256 + k) * 256 + (c - 256)];
    wcat3[t] = v;
    short hi, lo; f2b2(v, hi, lo);
    w3h[(size_t)c * 256 + k] = hi; w3l[(size_t)c * 256 + k] = lo;
  } else if (task == 3) {                 // wcat6 splitT only (F=256, Hc=39)
    if (t >= 256 * 78) return;
    int k = t / 78, c = t - k * 78;
    float v = (c < 39) ? w6[k * 39 + c] - w6[(256 + k) * 39 + c]
                       : w6[(256 + k) * 39 + (c - 39)];
    short hi, lo; f2b2(v, hi, lo);
    w6h[(size_t)c * 256 + k] = hi; w6l[(size_t)c * 256 + k] = lo;
  } else if (task == 4) {                 // lin4 splitT (256 x 256)
    if (t >= 256 * 256) return;
    int k = t >> 8, n = t & 255;
    short hi, lo; f2b2(l4[t], hi, lo);
    l4h[(size_t)n * 256 + k] = hi; l4l[(size_t)n * 256 + k] = lo;
  } else if (task == 5) {                 // lin5 splitT (256 x 128)
    if (t >= 256 * 128) return;
    int k = t >> 7, n = t & 127;
    short hi, lo; f2b2(l5[t], hi, lo);
    l5h[(size_t)n * 256 + k] = hi; l5l[(size_t)n * 256 + k] = lo;
  } else {                                // degree
    if (t >= B_ * N_) return;
    const float* row = adj + (size_t)t * N_;
    float s = 0.f;
    for (int j = 0; j < N_; ++j) s += row[j];
    deg[t] = s;
  }
}

// ---------------- fused gram + knn, G kept in LDS (block per graph) ----------------
__global__ __launch_bounds__(256) void gram_knn_kernel(const float* __restrict__ x, int n, int F,
                                                       int* __restrict__ idx) {
  extern __shared__ float xs[];
  int S = (F & 3) ? F + 5 : F + 4;
  float* Gs = xs + 40 * S;   // 40 x 41
  int b = blockIdx.x;
  const float* xb = x + (size_t)b * n * F;
  for (int t = threadIdx.x; t < 40 * S; t += 256) {
    int r = t / S, f = t - r * S;
    xs[t] = (r < n && f < F) ? xb[r * F + f] : 0.f;
  }
  __syncthreads();
  int rtiles = (n + 1) >> 1, ctiles = (n + 3) >> 2;
  for (int t = threadIdx.x; t < rtiles * ctiles; t += 256) {
    int rt = t % rtiles, ct = t / rtiles;   // rt fast -> B-side broadcast
    int i0 = rt * 2, j0 = ct * 4;
    float acc[2][4] = {};
    if ((F & 3) == 0) {
      for (int f = 0; f < F; f += 4) {
        float4 a0 = *(const float4*)&xs[i0 * S + f];
        float4 a1 = *(const float4*)&xs[(i0 + 1) * S + f];
#pragma unroll
        for (int j = 0; j < 4; ++j) {
          float4 bv = *(const float4*)&xs[(j0 + j) * S + f];
          acc[0][j] += a0.x * bv.x + a0.y * bv.y + a0.z * bv.z + a0.w * bv.w;
          acc[1][j] += a1.x * bv.x + a1.y * bv.y + a1.z * bv.z + a1.w * bv.w;
        }
      }
    } else {
      for (int f = 0; f < F; ++f) {
        float a0 = xs[i0 * S + f], a1 = xs[(i0 + 1) * S + f];
#pragma unroll
        for (int j = 0; j < 4; ++j) {
          float bv = xs[(j0 + j) * S + f];
          acc[0][j] += a0 * bv;
          acc[1][j] += a1 * bv;
        }
      }
    }
#pragma unroll
    for (int i = 0; i < 2; ++i) {
      if (i0 + i >= n) continue;
#pragma unroll
      for (int j = 0; j < 4; ++j) {
        if (j0 + j >= n) continue;
        Gs[(i0 + i) * 41 + (j0 + j)] = acc[i][j];
      }
    }
  }
  __syncthreads();
  int wave = threadIdx.x >> 6, lane = threadIdx.x & 63;
  for (int i = wave; i < n; i += 4) {
    float dcur = INFINITY;
    if (lane < n)
      dcur = Gs[i * 41 + i] + Gs[lane * 41 + lane] - 2.f * Gs[i * 41 + lane];
    int* outp = idx + (size_t)(b * n + i) * KNN_;
    for (int kk = 0; kk < KNN_; ++kk) {
      float rv = dcur;
      int rj = (lane < n) ? lane : (1 << 20);
      wave_argmin64(rv, rj);
      if (lane == 0) outp[kk] = rj;
      if (lane == rj) dcur = INFINITY;
    }
  }
}

// ---------------- fp32 trunk GEMM: 64x64 tile, register-staged pipeline ----------------
#define BM 64
#define BN 64
#define BK 16
__global__ __launch_bounds__(256) void gemm_kernel(
    const float* __restrict__ A, const float* __restrict__ W, const float* __restrict__ bias,
    float* __restrict__ C, int M, int N, int K, int act) {
  __shared__ float As[BK][BM + 4];
  __shared__ float Bs[BK][BN + 4];
  int tid = threadIdx.x;
  int tx = tid & 15, ty = tid >> 4;
  int row0 = blockIdx.y * BM, col0 = blockIdx.x * BN;
  float c[4][4] = {};
  float ra[4], rb[4];
#pragma unroll
  for (int v = 0; v < 4; ++v) {
    int e = tid + v * 256;
    int m = e >> 4, kk = e & 15;
    int row = row0 + m;
    ra[v] = (row < M && kk < K) ? A[(size_t)row * K + kk] : 0.f;
    int kk2 = e >> 6, nn = e & 63;
    int col = col0 + nn;
    rb[v] = (kk2 < K && col < N) ? W[(size_t)kk2 * N + col] : 0.f;
  }
  for (int k0 = 0; k0 < K; k0 += BK) {
#pragma unroll
    for (int v = 0; v < 4; ++v) {
      int e = tid + v * 256;
      As[e & 15][e >> 4] = ra[v];
      Bs[e >> 6][e & 63] = rb[v];
    }
    __syncthreads();
    int k1 = k0 + BK;
    if (k1 < K) {
#pragma unroll
      for (int v = 0; v < 4; ++v) {
        int e = tid + v * 256;
        int m = e >> 4, kk = e & 15;
        int row = row0 + m, k = k1 + kk;
        ra[v] = (row < M && k < K) ? A[(size_t)row * K + k] : 0.f;
        int kk2 = e >> 6, nn = e & 63;
        int k2 = k1 + kk2, col = col0 + nn;
        rb[v] = (k2 < K && col < N) ? W[(size_t)k2 * N + col] : 0.f;
      }
    }
#pragma unroll
    for (int kk = 0; kk < BK; ++kk) {
      float4 av = *(const float4*)&As[kk][ty * 4];
      float4 bv = *(const float4*)&Bs[kk][tx * 4];
      float a[4] = {av.x, av.y, av.z, av.w};
      float b[4] = {bv.x, bv.y, bv.z, bv.w};
#pragma unroll
      for (int i2 = 0; i2 < 4; ++i2)
#pragma unroll
        for (int j = 0; j < 4; ++j) c[i2][j] += a[i2] * b[j];
    }
    __syncthreads();
  }
#pragma unroll
  for (int i2 = 0; i2 < 4; ++i2) {
    int row = row0 + ty * 4 + i2;
    if (row >= M) continue;
#pragma unroll
    for (int j = 0; j < 4; ++j) {
      int col = col0 + tx * 4 + j;
      if (col >= N) continue;
      float v = c[i2][j] + (bias ? bias[col] : 0.f);
      if (act == 1) v = fmaxf(v, 0.f);
      C[(size_t)row * N + col] = v;
    }
  }
}

// ------------- split-bf16 3-pass MFMA GEMM (near-fp32 accuracy, ~2^-16 rel) -------------
__global__ __launch_bounds__(256) void mfma_gemm_split_kernel(
    const short* __restrict__ Ah, const short* __restrict__ Al,
    const short* __restrict__ Wth, const short* __restrict__ Wtl,
    const float* __restrict__ bias,
    float* __restrict__ C, short* __restrict__ Ch, short* __restrict__ Cl,
    int M, int N, int K, int act) {
  __shared__ short Ash[128 * 40];
  __shared__ short Asl[128 * 40];
  __shared__ short Bsh[128 * 40];
  __shared__ short Bsl[128 * 40];
  int tid = threadIdx.x;
  int wave = tid >> 6, lane = tid & 63;
  int wm = wave & 1, wn = wave >> 1;
  int row0 = blockIdx.y * 128, col0 = blockIdx.x * 128;
  floatx4 acc[4][4] = {};
  int lm = lane & 15, lk = (lane >> 4) * 8;
  for (int k0 = 0; k0 < K; k0 += 32) {
    for (int c = tid; c < 512; c += 256) {
      int r = c >> 2, kc = (c & 3) * 8;
      int grow = row0 + r;
      short8 vh = {}, vl = {};
      if (grow < M) {
        vh = *(const short8*)&Ah[(size_t)grow * K + k0 + kc];
        vl = *(const short8*)&Al[(size_t)grow * K + k0 + kc];
      }
      *(short8*)&Ash[r * 40 + kc] = vh;
      *(short8*)&Asl[r * 40 + kc] = vl;
    }
    for (int c = tid; c < 512; c += 256) {
      int r = c >> 2, kc = (c & 3) * 8;
      int gn = col0 + r;
      short8 vh = {}, vl = {};
      if (gn < N) {
        vh = *(const short8*)&Wth[(size_t)gn * K + k0 + kc];
        vl = *(const short8*)&Wtl[(size_t)gn * K + k0 + kc];
      }
      *(short8*)&Bsh[r * 40 + kc] = vh;
      *(short8*)&Bsl[r * 40 + kc] = vl;
    }
    __syncthreads();
    short8 afh[4], afl[4], bfh[4], bfl[4];
#pragma unroll
    for (int mi = 0; mi < 4; ++mi) {
      int ro = (wm * 64 + mi * 16 + lm) * 40 + lk;
      afh[mi] = *(const short8*)&Ash[ro];
      afl[mi] = *(const short8*)&Asl[ro];
    }
#pragma unroll
    for (int ni = 0; ni < 4; ++ni) {
      int ro = (wn * 64 + ni * 16 + lm) * 40 + lk;
      bfh[ni] = *(const short8*)&Bsh[ro];
      bfl[ni] = *(const short8*)&Bsl[ro];
    }
#pragma unroll
    for (int mi = 0; mi < 4; ++mi)
#pragma unroll
      for (int ni = 0; ni < 4; ++ni) {
        acc[mi][ni] = __builtin_amdgcn_mfma_f32_16x16x32_bf16(afh[mi], bfh[ni], acc[mi][ni], 0, 0, 0);
        acc[mi][ni] = __builtin_amdgcn_mfma_f32_16x16x32_bf16(afh[mi], bfl[ni], acc[mi][ni], 0, 0, 0);
        acc[mi][ni] = __builtin_amdgcn_mfma_f32_16x16x32_bf16(afl[mi], bfh[ni], acc[mi][ni], 0, 0, 0);
      }
    __syncthreads();
  }
  int lr = (lane >> 4) * 4;
#pragma unroll
  for (int mi = 0; mi < 4; ++mi)
#pragma unroll
    for (int ni = 0; ni < 4; ++ni) {
      int colg = col0 + wn * 64 + ni * 16 + lm;
      if (colg >= N) continue;
      float bv = bias ? bias[colg] : 0.f;
#pragma unroll
      for (int r = 0; r < 4; ++r) {
        int rowg = row0 + wm * 64 + mi * 16 + lr + r;
        if (rowg >= M) continue;
        float v = acc[mi][ni][r] + bv;
        if (act == 1) v = fmaxf(v, 0.f);
        C[(size_t)rowg * N + colg] = v;
        if (Ch) {
          short hi, lo;
          f2b2(v, hi, lo);
          Ch[(size_t)rowg * N + colg] = hi;
          Cl[(size_t)rowg * N + colg] = lo;
        }
      }
    }
}

// Thin GEMM (small M): one block per row.
__global__ __launch_bounds__(256) void rowgemm_kernel(
    const float* __restrict__ A, const float* __restrict__ W, const float* __restrict__ bias,
    float* __restrict__ C, int N, int K, int act) {
  __shared__ float a[512];
  int row = blockIdx.x;
  for (int k = threadIdx.x; k < K; k += 256) a[k] = A[(size_t)row * K + k];
  __syncthreads();
  for (int c = threadIdx.x; c < N; c += 256) {
    float s = 0.f;
    for (int k = 0; k < K; k += 4) {
      float4 av = *(const float4*)&a[k];
      s += av.x * W[(size_t)k * N + c];
      s += av.y * W[(size_t)(k + 1) * N + c];
      s += av.z * W[(size_t)(k + 2) * N + c];
      s += av.w * W[(size_t)(k + 3) * N + c];
    }
    float v = s + (bias ? bias[c] : 0.f);
    if (act == 1) v = fmaxf(v, 0.f);
    C[(size_t)row * N + c] = v;
  }
}

// one wave per output element (for very small M*N)
__global__ void wavedot_gemm_kernel(const float* __restrict__ A, const float* __restrict__ W,
                                    const float* __restrict__ bias, float* __restrict__ C,
                                    int M, int N, int K, int act) {
  int wid = (blockIdx.x * blockDim.x + threadIdx.x) >> 6;
  int lane = threadIdx.x & 63;
  if (wid >= M * N) return;
  int row = wid / N, col = wid - row * N;
  const float* ar = A + (size_t)row * K;
  float s = 0.f;
  for (int k = lane; k < K; k += 64) s += ar[k] * W[(size_t)k * N + col];
  for (int off = 32; off; off >>= 1) s += __shfl_down(s, off, 64);
  if (lane == 0) {
    float v = s + (bias ? bias[col] : 0.f);
    if (act == 1) v = fmaxf(v, 0.f);
    C[(size_t)row * N + col] = v;
  }
}

// AB row r: [0..Hc) = xi@(Wt-Wb), [Hc..2Hc) = xi@Wb.  out = max_k relu(Ai + b + Bm[nbr]) [tanh]
__global__ void edge_agg_kernel(const float* __restrict__ AB, const float* __restrict__ bias,
                                const int* __restrict__ idx, int n, int Hc, int act,
                                float* __restrict__ out,
                                short* __restrict__ outh, short* __restrict__ outl) {
  int t = blockIdx.x * blockDim.x + threadIdx.x;
  if (t >= B_ * n * Hc) return;
  int r = t / Hc, h = t - r * Hc;
  int b = r / n;
  int s2 = 2 * Hc;
  float av = AB[(size_t)r * s2 + h] + bias[h];
  const int* ir = idx + (size_t)r * KNN_;
  int base = b * n;
  float m = -INFINITY;
  for (int k = 0; k < KNN_; ++k) {
    float v = av + AB[(size_t)(base + ir[k]) * s2 + Hc + h];
    v = fmaxf(v, 0.f);
    m = fmaxf(m, v);
  }
  if (act == 2) m = tanhf(m);
  out[t] = m;
  if (outh) {
    short hi, lo;
    f2b2(m, hi, lo);
    outh[t] = hi;
    outl[t] = lo;
  }
}

__global__ void bn_stats_kernel(const float* __restrict__ x, int M, float* __restrict__ mv) {
  int c = blockIdx.x;
  double s = 0.0, s2 = 0.0;
  for (int r = threadIdx.x; r < M; r += 256) {
    double v = (double)x[(size_t)r * H_ + c];
    s += v; s2 += v * v;
  }
  __shared__ double sh[256], sh2[256];
  sh[threadIdx.x] = s; sh2[threadIdx.x] = s2;
  __syncthreads();
  for (int o = 128; o; o >>= 1) {
    if (threadIdx.x < o) { sh[threadIdx.x] += sh[threadIdx.x + o]; sh2[threadIdx.x] += sh2[threadIdx.x + o]; }
    __syncthreads();
  }
  if (threadIdx.x == 0) {
    double mean = sh[0] / M;
    double var = sh2[0] / M - mean * mean;
    mv[c] = (float)mean;
    mv[H_ + c] = (float)var;
  }
}

__global__ void bn_apply_kernel(const float* __restrict__ x, const float* __restrict__ mv,
                                const float* __restrict__ g, const float* __restrict__ bb,
                                int M, float* __restrict__ out) {
  int t = blockIdx.x * blockDim.x + threadIdx.x;
  if (t >= M * H_) return;
  int h = t & (H_ - 1);
  float mean = mv[h], var = mv[H_ + h];
  float v = (x[t] - mean) * (1.f / sqrtf(var + 1e-5f)) * g[h] + bb[h];
  out[t] = fmaxf(v, 0.f);
}

// one wave per row: y[r] = dot(x[r,:K], w) [+bias] [relu]
__global__ void rowdot_kernel(const float* __restrict__ x, const float* __restrict__ w,
                              int M, int K, const float* __restrict__ bias, int act,
                              float* __restrict__ y) {
  int wid = (blockIdx.x * blockDim.x + threadIdx.x) >> 6;
  int lane = threadIdx.x & 63;
  if (wid >= M) return;
  const float* xr = x + (size_t)wid * K;
  float s = 0.f;
  for (int k = lane; k < K; k += 64) s += xr[k] * w[k];
  for (int off = 32; off; off >>= 1) s += __shfl_down(s, off, 64);
  if (lane == 0) {
    float v = s + (bias ? bias[0] : 0.f);
    if (act == 1) v = fmaxf(v, 0.f);
    y[wid] = v;
  }
}

// ---------------- fused SAG pool: rowdot + gcn score + topk + gather (block per graph) ----------------
__global__ __launch_bounds__(256) void sag_kernel(
    const float* __restrict__ h, const float* __restrict__ adj_in, int n, int k,
    const float* __restrict__ pw, const float* __restrict__ pb,
    int* __restrict__ perm, float* __restrict__ xp, float* __restrict__ adjp) {
  __shared__ float ys[40], dinv[40], sc[40], topv[40];
  __shared__ int locs[40];
  int b = blockIdx.x;
  int wave = threadIdx.x >> 6, lane = threadIdx.x & 63;
  // rowdot: y[i] = h[b,i,:] . pw
  for (int i = wave; i < n; i += 4) {
    const float* xr = h + (size_t)(b * n + i) * H_;
    float s = 0.f;
    for (int kk = lane; kk < H_; kk += 64) s += xr[kk] * pw[kk];
    for (int off = 32; off; off >>= 1) s += __shfl_down(s, off, 64);
    if (lane == 0) ys[i] = s;
  }
  __syncthreads();
  int i = threadIdx.x;
  if (i < n) {
    const float* ar = adj_in + ((size_t)b * n + i) * n;
    float sum = 1.f;
    for (int j = 0; j < n; ++j) sum += ar[j];
    dinv[i] = 1.f / sqrtf(sum);
  }
  __syncthreads();
  if (i < n) {
    const float* ar = adj_in + ((size_t)b * n + i) * n;
    float acc = 0.f;
    for (int j = 0; j < n; ++j) {
      float a = ar[j] + (i == j ? 1.f : 0.f);
      acc += a * dinv[j] * ys[j];
    }
    sc[i] = dinv[i] * acc + pb[0];
  }
  __syncthreads();
  if (wave == 0) {
    float cur = (lane < n) ? sc[lane] : -INFINITY;
    for (int t = 0; t < k; ++t) {
      float rv = cur;
      int rj = (lane < n) ? lane : (1 << 20);
      wave_argmax64(rv, rj);
      if (lane == 0) { topv[t] = rv; locs[t] = rj; perm[b * k + t] = b * n + rj; }
      if (lane == rj) cur = -INFINITY;
    }
  }
  __syncthreads();
  for (int e = threadIdx.x; e < k * H_; e += 256) {
    int r = e >> 8, hh = e & 255;
    xp[((size_t)b * k + r) * H_ + hh] =
        h[((size_t)(b * n + locs[r])) * H_ + hh] * tanhf(topv[r]);
  }
  if (adjp) {
    for (int e = threadIdx.x; e < k * k; e += 256) {
      int t1 = e / k, t2 = e - t1 * k;
      adjp[(size_t)b * k * k + e] = adj_in[((size_t)b * n + locs[t1]) * n + locs[t2]];
    }
  }
}

// dst[i1[i2[r]] or i1[r]] = src[r]; fp32 + split-bf16 (all pre-zeroed)
__global__ void scatter_kernel(const float* __restrict__ src, const int* __restrict__ i1,
                               const int* __restrict__ i2, int rows,
                               float* __restrict__ dst,
                               short* __restrict__ dsth, short* __restrict__ dstl) {
  int t = blockIdx.x * blockDim.x + threadIdx.x;
  if (t >= rows * H_) return;
  int r = t / H_, h = t - r * H_;
  int tgt = i2 ? i1[i2[r]] : i1[r];
  float v = src[t];
  dst[(size_t)tgt * H_ + h] = v;
  short hi, lo;
  f2b2(v, hi, lo);
  dsth[(size_t)tgt * H_ + h] = hi;
  dstl[(size_t)tgt * H_ + h] = lo;
}

__global__ void gtpred_kernel(const float* __restrict__ deg, const float* __restrict__ xdeg,
                              const int* __restrict__ perm, int M,
                              float* __restrict__ gt, float* __restrict__ pred) {
  int t = blockIdx.x * blockDim.x + threadIdx.x;
  if (t >= M) return;
  int p = perm[t];
  gt[t] = deg[p];
  pred[t] = xdeg[p];
}

__global__ void readout_kernel(const float* __restrict__ xp, int k, int acc, float* __restrict__ z) {
  int t = blockIdx.x * blockDim.x + threadIdx.x;
  if (t >= B_ * H_) return;
  int b = t / H_, h = t - b * H_;
  float mx = -INFINITY, sm = 0.f;
  for (int tt = 0; tt < k; ++tt) {
    float v = xp[((size_t)b * k + tt) * H_ + h];
    mx = fmaxf(mx, v);
    sm += v;
  }
  float* zb = z + (size_t)b * 2 * H_;
  float mean = sm / (float)k;
  if (acc) { zb[h] += mx; zb[H_ + h] += mean; }
  else     { zb[h] = mx;  zb[H_ + h] = mean; }
}

__global__ void softmax2_kernel(const float* __restrict__ logits, float* __restrict__ probs) {
  int b = blockIdx.x * blockDim.x + threadIdx.x;
  if (b >= B_) return;
  float a = logits[2 * b], c = logits[2 * b + 1];
  float m = fmaxf(a, c);
  float ea = expf(a - m), ec = expf(c - m);
  float inv = 1.f / (ea + ec);
  probs[2 * b] = ea * inv;
  probs[2 * b + 1] = ec * inv;
}

extern "C" void kernel_launch(void* const* d_in, const int* in_sizes, int n_in,
                              void* d_out, int out_size, void* d_ws, size_t ws_size,
                              hipStream_t stream) {
  auto in = [&](int i) { return (const float*)d_in[i]; };
  const float* x      = in(0);
  const float* adj    = in(1);
  const float* w_mlp1 = in(2);  const float* b_mlp1 = in(3);
  const float* w_mlp2 = in(4);  const float* b_mlp2 = in(5);
  const float* w_mlp3 = in(6);  const float* b_mlp3 = in(7);
  const float* w_mlp6 = in(8);  const float* b_mlp6 = in(9);
  const float* bn1_g = in(10);  const float* bn1_b = in(11);
  const float* bn2_g = in(12);  const float* bn2_b = in(13);
  const float* bn3_g = in(14);  const float* bn3_b = in(15);
  const float* p1_w = in(16);   const float* p1_b = in(17);
  const float* p2_w = in(18);   const float* p2_b = in(19);
  const float* p3_w = in(20);   const float* p3_b = in(21);
  const float* lin1_w = in(22); const float* lin1_b = in(23);
  const float* lin2_w = in(24); const float* lin2_b = in(25);
  const float* lin3_w = in(26); const float* lin3_b = in(27);
  const float* lin4_w = in(28); const float* lin4_b = in(29);
  const float* lin5_w = in(30); const float* lin5_b = in(31);
  const float* lin6_w = in(32); const float* lin6_b = in(33);

  float* out = (float*)d_out;
  float* out_probs = out;                      // 128*2
  float* out_dec1  = out_probs + 256;          // 4992*39
  float* out_dec2  = out_dec1 + 4992 * 39;
  float* out_dec3  = out_dec2 + 4992 * 39;
  float* out_gt1   = out_dec3 + 4992 * 39;     // 4096
  float* out_pred1 = out_gt1 + 4096;           // 4096
  float* out_gt2   = out_pred1 + 4096;         // 3328
  float* out_pred2 = out_gt2 + 3328;
  float* out_gt3   = out_pred2 + 3328;         // 2688
  float* out_pred3 = out_gt3 + 2688;

  char* base = (char*)d_ws;
  size_t off = 0;
  auto allocf = [&](size_t n) -> float* {
    float* p = (float*)(base + off);
    off += ((n * sizeof(float) + 255) & ~(size_t)255);
    return p;
  };
  auto alloci = [&](size_t n) -> int* {
    int* p = (int*)(base + off);
    off += ((n * sizeof(int) + 255) & ~(size_t)255);
    return p;
  };
  auto allocs = [&](size_t n) -> short* {
    short* p = (short*)(base + off);
    off += ((n * sizeof(short) + 255) & ~(size_t)255);
    return p;
  };

  float* wcat1 = allocf(39 * 512);
  float* wcat2 = allocf(256 * 512);
  float* wcat3 = allocf(256 * 512);
  short* wcat2t_h = allocs(512 * 256); short* wcat2t_l = allocs(512 * 256);
  short* wcat3t_h = allocs(512 * 256); short* wcat3t_l = allocs(512 * 256);
  short* wcat6t_h = allocs(78 * 256);  short* wcat6t_l = allocs(78 * 256);
  short* lin4t_h  = allocs(256 * 256); short* lin4t_l  = allocs(256 * 256);
  short* lin5t_h  = allocs(128 * 256); short* lin5t_l  = allocs(128 * 256);
  float* deg   = allocf(4992);
  float* xdeg  = allocf(4992);
  int*   idxb  = alloci(4992 * KNN_);
  float* AB    = allocf((size_t)4992 * 512);
  float* t1    = allocf((size_t)4992 * 256);
  float* t2    = allocf((size_t)4992 * 256);
  float* hbuf  = allocf((size_t)4992 * 256);
  float* xp    = allocf((size_t)4096 * 256);
  size_t ms0 = off;                             // contiguous memset region start
  float* xout  = allocf((size_t)4992 * 256);
  short* xout_h = allocs((size_t)4992 * 256);
  short* xout_l = allocs((size_t)4992 * 256);
  size_t msz = off - ms0;                       // one memset covers xout + both bf16 copies
  short* t1_h   = allocs((size_t)4992 * 256); short* t1_l   = allocs((size_t)4992 * 256);
  short* t2_h   = allocs((size_t)4992 * 256); short* t2_l   = allocs((size_t)4992 * 256);
  float* adj1  = allocf(128 * 32 * 32);
  float* adj2  = allocf(128 * 26 * 26);
  float* stats = allocf(512);
  int* perm1 = alloci(4096); int* perm2 = alloci(3328); int* perm3 = alloci(2688);
  float* z  = allocf(128 * 512);
  float* z1 = allocf(128 * 256);
  float* z2 = allocf(128 * 128);
  float* logits = allocf(256);
  if (off > ws_size) return;

  auto glds = [](int F) -> size_t {
    int S = (F & 3) ? F + 5 : F + 4;
    return (size_t)(40 * S + 40 * 41) * sizeof(float);
  };

  // fp32 trunk edge conv (feeds top-k; exact)
  auto edge_conv = [&](const float* xin, int n, int F, const float* wcat, const float* bias,
                       int Hout, float* outbuf) {
    int M = B_ * n;
    gram_knn_kernel<<<B_, 256, glds(F), stream>>>(xin, n, F, idxb);
    dim3 gg(cdiv(2 * Hout, BN), cdiv(M, BM));
    gemm_kernel<<<gg, 256, 0, stream>>>(xin, wcat, nullptr, AB, M, 2 * Hout, F, 0);
    edge_agg_kernel<<<cdiv(M * Hout, 256), 256, 0, stream>>>(AB, bias, idxb, n, Hout, 0, outbuf, nullptr, nullptr);
  };
  // split-bf16 decoder edge conv
  auto edge_conv_bf = [&](const float* xin, const short* xh, const short* xl,
                          const short* wth, const short* wtl,
                          const float* bias, int Hout, int act,
                          float* outbuf, short* outh, short* outl) {
    int M = 4992, F = 256;
    gram_knn_kernel<<<B_, 256, glds(F), stream>>>(xin, N_, F, idxb);
    dim3 gg(cdiv(2 * Hout, 128), cdiv(M, 128));
    mfma_gemm_split_kernel<<<gg, 256, 0, stream>>>(xh, xl, wth, wtl, nullptr, AB, nullptr, nullptr,
                                                   M, 2 * Hout, F, 0);
    edge_agg_kernel<<<cdiv(M * Hout, 256), 256, 0, stream>>>(AB, bias, idxb, N_, Hout, act, outbuf, outh, outl);
  };
  auto decoder = [&](const float* xin, const short* xh, const short* xl, float* decout) {
    edge_conv_bf(xin, xh, xl, wcat3t_h, wcat3t_l, b_mlp3, H_, 2, t1, t1_h, t1_l);
    edge_conv_bf(t1, t1_h, t1_l, wcat2t_h, wcat2t_l, b_mlp2, H_, 2, t2, t2_h, t2_l);
    edge_conv_bf(t2, t2_h, t2_l, wcat6t_h, wcat6t_l, b_mlp6, N_, 0, decout, nullptr, nullptr);
  };

  // ---- one-shot prep ----
  prep_kernel<<<dim3(512, 7), 256, 0, stream>>>(
      w_mlp1, w_mlp2, w_mlp3, w_mlp6, lin4_w, lin5_w, adj,
      wcat1, wcat2, wcat3,
      wcat2t_h, wcat2t_l, wcat3t_h, wcat3t_l, wcat6t_h, wcat6t_l,
      lin4t_h, lin4t_l, lin5t_h, lin5t_l, deg);

  // ---- level 1 ----
  edge_conv(x, N_, N_, wcat1, b_mlp1, H_, t1);
  bn_stats_kernel<<<H_, 256, 0, stream>>>(t1, 4992, stats);
  bn_apply_kernel<<<cdiv(4992 * 256, 256), 256, 0, stream>>>(t1, stats, bn1_g, bn1_b, 4992, hbuf);
  sag_kernel<<<B_, 256, 0, stream>>>(hbuf, adj, N_, K1_, p1_w, p1_b, perm1, xp, adj1);
  hipMemsetAsync(xout, 0, msz, stream);
  scatter_kernel<<<cdiv(4096 * 256, 256), 256, 0, stream>>>(xp, perm1, nullptr, 4096, xout, xout_h, xout_l);
  {
    dim3 g4(2, 39);
    mfma_gemm_split_kernel<<<g4, 256, 0, stream>>>(xout_h, xout_l, lin4t_h, lin4t_l, lin4_b,
                                                   t1, t1_h, t1_l, 4992, 256, 256, 1);
    dim3 g5(1, 39);
    mfma_gemm_split_kernel<<<g5, 256, 0, stream>>>(t1_h, t1_l, lin5t_h, lin5t_l, lin5_b,
                                                   t2, nullptr, nullptr, 4992, 128, 256, 1);
  }
  rowdot_kernel<<<cdiv(4992 * 64, 256), 256, 0, stream>>>(t2, lin6_w, 4992, 128, lin6_b, 1, xdeg);
  gtpred_kernel<<<cdiv(4096, 256), 256, 0, stream>>>(deg, xdeg, perm1, 4096, out_gt1, out_pred1);
  readout_kernel<<<cdiv(128 * 256, 256), 256, 0, stream>>>(xp, K1_, 0, z);
  decoder(xout, xout_h, xout_l, out_dec1);

  // ---- level 2 ----
  edge_conv(xp, K1_, H_, wcat2, b_mlp2, H_, t1);
  bn_stats_kernel<<<H_, 256, 0, stream>>>(t1, 4096, stats);
  bn_apply_kernel<<<cdiv(4096 * 256, 256), 256, 0, stream>>>(t1, stats, bn2_g, bn2_b, 4096, hbuf);
  sag_kernel<<<B_, 256, 0, stream>>>(hbuf, adj1, K1_, K2_, p2_w, p2_b, perm2, xp, adj2);
  hipMemsetAsync(xout, 0, msz, stream);
  scatter_kernel<<<cdiv(3328 * 256, 256), 256, 0, stream>>>(xp, perm1, perm2, 3328, xout, xout_h, xout_l);
  gtpred_kernel<<<cdiv(3328, 256), 256, 0, stream>>>(deg, xdeg, perm2, 3328, out_gt2, out_pred2);
  readout_kernel<<<cdiv(128 * 256, 256), 256, 0, stream>>>(xp, K2_, 1, z);
  decoder(xout, xout_h, xout_l, out_dec2);

  // ---- level 3 ----
  edge_conv(xp, K2_, H_, wcat3, b_mlp3, H_, t1);
  bn_stats_kernel<<<H_, 256, 0, stream>>>(t1, 3328, stats);
  bn_apply_kernel<<<cdiv(3328 * 256, 256), 256, 0, stream>>>(t1, stats, bn3_g, bn3_b, 3328, hbuf);
  sag_kernel<<<B_, 256, 0, stream>>>(hbuf, adj2, K2_, K3_, p3_w, p3_b, perm3, xp, nullptr);
  hipMemsetAsync(xout, 0, msz, stream);
  scatter_kernel<<<cdiv(2688 * 256, 256), 256, 0, stream>>>(xp, perm2, perm3, 2688, xout, xout_h, xout_l);
  gtpred_kernel<<<cdiv(2688, 256), 256, 0, stream>>>(deg, xdeg, perm3, 2688, out_gt3, out_pred3);
  readout_kernel<<<cdiv(128 * 256, 256), 256, 0, stream>>>(xp, K3_, 1, z);
  decoder(xout, xout_h, xout_l, out_dec3);

  // ---- classifier head (thin: M=128) ----
  rowgemm_kernel<<<128, 256, 0, stream>>>(z, lin1_w, lin1_b, z1, 256, 512, 1);
  rowgemm_kernel<<<128, 256, 0, stream>>>(z1, lin2_w, lin2_b, z2, 128, 256, 1);
  wavedot_gemm_kernel<<<cdiv(128 * 2 * 64, 256), 256, 0, stream>>>(z2, lin3_w, lin3_b, logits, 128, 2, 128, 0);
  softmax2_kernel<<<1, 128, 0, stream>>>(logits, out_probs);
}

// Round 7
// 1251.175 us; speedup vs baseline: 1.3857x; 1.3857x over previous
//
#include <hip/hip_runtime.h>
#include <cmath>

#define B_   128
#define N_   39
#define KNN_ 10
#define H_   256
#define K1_  32
#define K2_  26
#define K3_  21
#define GSPLIT 4

static inline int cdiv(int a, int b) { return (a + b - 1) / b; }

typedef __attribute__((ext_vector_type(8))) short short8;
typedef __attribute__((ext_vector_type(4))) float floatx4;

__device__ inline short f2b(float f) {   // fp32 -> bf16 RNE
  unsigned u = __float_as_uint(f);
  u += 0x7fff + ((u >> 16) & 1);
  return (short)(u >> 16);
}
__device__ inline float b2f(short h) {
  return __uint_as_float(((unsigned)(unsigned short)h) << 16);
}
__device__ inline void f2b2(float v, short& hi, short& lo) {  // split: v ~= hi + lo
  hi = f2b(v);
  lo = f2b(v - b2f(hi));
}

// ---------- wave-wide argmax/argmin (64 lanes), ties -> lowest index ----------
__device__ inline void wave_argmax64(float& v, int& j) {
#pragma unroll
  for (int off = 32; off; off >>= 1) {
    float ov = __shfl_down(v, off, 64);
    int   oj = __shfl_down(j, off, 64);
    if (ov > v || (ov == v && oj < j)) { v = ov; j = oj; }
  }
  v = __shfl(v, 0, 64);
  j = __shfl(j, 0, 64);
}
__device__ inline void wave_argmin64(float& v, int& j) {
#pragma unroll
  for (int off = 32; off; off >>= 1) {
    float ov = __shfl_down(v, off, 64);
    int   oj = __shfl_down(j, off, 64);
    if (ov < v || (ov == v && oj < j)) { v = ov; j = oj; }
  }
  v = __shfl(v, 0, 64);
  j = __shfl(j, 0, 64);
}

// ---------------- one-shot weight prep + degree (7 tasks on blockIdx.y) ----------------
__global__ void prep_kernel(const float* __restrict__ w1, const float* __restrict__ w2,
                            const float* __restrict__ w3, const float* __restrict__ w6,
                            const float* __restrict__ l4, const float* __restrict__ l5,
                            const float* __restrict__ adj,
                            float* __restrict__ wcat1, float* __restrict__ wcat2,
                            float* __restrict__ wcat3,
                            short* __restrict__ w2h, short* __restrict__ w2l,
                            short* __restrict__ w3h, short* __restrict__ w3l,
                            short* __restrict__ w6h, short* __restrict__ w6l,
                            short* __restrict__ l4h, short* __restrict__ l4l,
                            short* __restrict__ l5h, short* __restrict__ l5l,
                            float* __restrict__ deg) {
  int task = blockIdx.y;
  int t = blockIdx.x * 256 + threadIdx.x;
  if (task == 0) {                        // wcat1 fp32 only (F=39, Hc=256)
    if (t >= 39 * 512) return;
    int k = t >> 9, c = t & 511;
    wcat1[t] = (c < 256) ? w1[k * 256 + c] - w1[(39 + k) * 256 + c]
                         : w1[(39 + k) * 256 + (c - 256)];
  } else if (task == 1) {                 // wcat2 fp32 + splitT (F=256, Hc=256)
    if (t >= 256 * 512) return;
    int k = t >> 9, c = t & 511;
    float v = (c < 256) ? w2[k * 256 + c] - w2[(256 + k) * 256 + c]
                        : w2[(256 + k) * 256 + (c - 256)];
    wcat2[t] = v;
    short hi, lo; f2b2(v, hi, lo);
    w2h[(size_t)c * 256 + k] = hi; w2l[(size_t)c * 256 + k] = lo;
  } else if (task == 2) {                 // wcat3 fp32 + splitT
    if (t >= 256 * 512) return;
    int k = t >> 9, c = t & 511;
    float v = (c < 256) ? w3[k * 256 + c] - w3[(256 + k) * 256 + c]
                        : w3[(256 + k) * 256 + (c - 256)];
    wcat3[t] = v;
    short hi, lo; f2b2(v, hi, lo);
    w3h[(size_t)c * 256 + k] = hi; w3l[(size_t)c * 256 + k] = lo;
  } else if (task == 3) {                 // wcat6 splitT only (F=256, Hc=39)
    if (t >= 256 * 78) return;
    int k = t / 78, c = t - k * 78;
    float v = (c < 39) ? w6[k * 39 + c] - w6[(256 + k) * 39 + c]
                       : w6[(256 + k) * 39 + (c - 39)];
    short hi, lo; f2b2(v, hi, lo);
    w6h[(size_t)c * 256 + k] = hi; w6l[(size_t)c * 256 + k] = lo;
  } else if (task == 4) {                 // lin4 splitT (256 x 256)
    if (t >= 256 * 256) return;
    int k = t >> 8, n = t & 255;
    short hi, lo; f2b2(l4[t], hi, lo);
    l4h[(size_t)n * 256 + k] = hi; l4l[(size_t)n * 256 + k] = lo;
  } else if (task == 5) {                 // lin5 splitT (256 x 128)
    if (t >= 256 * 128) return;
    int k = t >> 7, n = t & 127;
    short hi, lo; f2b2(l5[t], hi, lo);
    l5h[(size_t)n * 256 + k] = hi; l5l[(size_t)n * 256 + k] = lo;
  } else {                                // degree
    if (t >= B_ * N_) return;
    const float* row = adj + (size_t)t * N_;
    float s = 0.f;
    for (int j = 0; j < N_; ++j) s += row[j];
    deg[t] = s;
  }
}

// ---------------- gram+knn, register-resident G rows ----------------
// grid (B_, GSPLIT); block 256. Each wave owns output row i; lane j holds G[i][j].
// A-side LDS reads are wave-uniform (broadcast, free); per-lane diag in registers.
__global__ __launch_bounds__(256) void gram_knn_kernel(const float* __restrict__ x, int n, int F,
                                                       int* __restrict__ idx) {
  extern __shared__ float xs[];
  int S = (F & 3) ? (F + 5) : (F + 4);
  int b = blockIdx.x;
  int rows_pb = (n + GSPLIT - 1) / GSPLIT;
  int r0 = blockIdx.y * rows_pb;
  int rend = r0 + rows_pb; if (rend > n) rend = n;
  const float* xb = x + (size_t)b * n * F;
  for (int t = threadIdx.x; t < 40 * S; t += 256) {
    int r = t / S, f = t - r * S;
    xs[t] = (r < n && f < F) ? xb[r * F + f] : 0.f;
  }
  __syncthreads();
  int wave = threadIdx.x >> 6, lane = threadIdx.x & 63;
  int jr = (lane < 40) ? lane : 0;           // clamp: lanes >= 40 are inactive
  const float* xj = &xs[jr * S];
  // per-lane diagonal: G[j][j]
  float diag;
  if (F & 3) {
    float a0 = 0.f;
    for (int f = 0; f < F; ++f) { float v = xj[f]; a0 += v * v; }
    diag = a0;
  } else {
    float a0 = 0.f, a1 = 0.f, a2 = 0.f, a3 = 0.f;
    for (int f = 0; f < F; f += 4) {
      float4 v = *(const float4*)&xj[f];
      a0 += v.x * v.x; a1 += v.y * v.y; a2 += v.z * v.z; a3 += v.w * v.w;
    }
    diag = (a0 + a1) + (a2 + a3);
  }
  for (int i = r0 + wave; i < rend; i += 4) {
    const float* xi = &xs[i * S];
    float g;
    if (F & 3) {
      float a0 = 0.f;
      for (int f = 0; f < F; ++f) a0 += xi[f] * xj[f];
      g = a0;
    } else {
      float a0 = 0.f, a1 = 0.f, a2 = 0.f, a3 = 0.f;
      for (int f = 0; f < F; f += 4) {
        float4 a = *(const float4*)&xi[f];
        float4 bv = *(const float4*)&xj[f];
        a0 += a.x * bv.x; a1 += a.y * bv.y; a2 += a.z * bv.z; a3 += a.w * bv.w;
      }
      g = (a0 + a1) + (a2 + a3);
    }
    float gii = __shfl(diag, i, 64);
    float d = (lane < n) ? (gii + diag - 2.f * g) : INFINITY;
    int* outp = idx + (size_t)(b * n + i) * KNN_;
    for (int kk = 0; kk < KNN_; ++kk) {
      float rv = d;
      int rj = (lane < n) ? lane : (1 << 20);
      wave_argmin64(rv, rj);
      if (lane == 0) outp[kk] = rj;
      if (lane == rj) d = INFINITY;
    }
  }
}

// ---------------- fp32 trunk GEMM: 64x64 tile, register-staged pipeline ----------------
#define BM 64
#define BN 64
#define BK 16
__global__ __launch_bounds__(256) void gemm_kernel(
    const float* __restrict__ A, const float* __restrict__ W, const float* __restrict__ bias,
    float* __restrict__ C, int M, int N, int K, int act) {
  __shared__ float As[BK][BM + 4];
  __shared__ float Bs[BK][BN + 4];
  int tid = threadIdx.x;
  int tx = tid & 15, ty = tid >> 4;
  int row0 = blockIdx.y * BM, col0 = blockIdx.x * BN;
  float c[4][4] = {};
  float ra[4], rb[4];
#pragma unroll
  for (int v = 0; v < 4; ++v) {
    int e = tid + v * 256;
    int m = e >> 4, kk = e & 15;
    int row = row0 + m;
    ra[v] = (row < M && kk < K) ? A[(size_t)row * K + kk] : 0.f;
    int kk2 = e >> 6, nn = e & 63;
    int col = col0 + nn;
    rb[v] = (kk2 < K && col < N) ? W[(size_t)kk2 * N + col] : 0.f;
  }
  for (int k0 = 0; k0 < K; k0 += BK) {
#pragma unroll
    for (int v = 0; v < 4; ++v) {
      int e = tid + v * 256;
      As[e & 15][e >> 4] = ra[v];
      Bs[e >> 6][e & 63] = rb[v];
    }
    __syncthreads();
    int k1 = k0 + BK;
    if (k1 < K) {
#pragma unroll
      for (int v = 0; v < 4; ++v) {
        int e = tid + v * 256;
        int m = e >> 4, kk = e & 15;
        int row = row0 + m, k = k1 + kk;
        ra[v] = (row < M && k < K) ? A[(size_t)row * K + k] : 0.f;
        int kk2 = e >> 6, nn = e & 63;
        int k2 = k1 + kk2, col = col0 + nn;
        rb[v] = (k2 < K && col < N) ? W[(size_t)k2 * N + col] : 0.f;
      }
    }
#pragma unroll
    for (int kk = 0; kk < BK; ++kk) {
      float4 av = *(const float4*)&As[kk][ty * 4];
      float4 bv = *(const float4*)&Bs[kk][tx * 4];
      float a[4] = {av.x, av.y, av.z, av.w};
      float b[4] = {bv.x, bv.y, bv.z, bv.w};
#pragma unroll
      for (int i2 = 0; i2 < 4; ++i2)
#pragma unroll
        for (int j = 0; j < 4; ++j) c[i2][j] += a[i2] * b[j];
    }
    __syncthreads();
  }
#pragma unroll
  for (int i2 = 0; i2 < 4; ++i2) {
    int row = row0 + ty * 4 + i2;
    if (row >= M) continue;
#pragma unroll
    for (int j = 0; j < 4; ++j) {
      int col = col0 + tx * 4 + j;
      if (col >= N) continue;
      float v = c[i2][j] + (bias ? bias[col] : 0.f);
      if (act == 1) v = fmaxf(v, 0.f);
      C[(size_t)row * N + col] = v;
    }
  }
}

// ------------- split-bf16 3-pass MFMA GEMM (near-fp32 accuracy, ~2^-16 rel) -------------
__global__ __launch_bounds__(256) void mfma_gemm_split_kernel(
    const short* __restrict__ Ah, const short* __restrict__ Al,
    const short* __restrict__ Wth, const short* __restrict__ Wtl,
    const float* __restrict__ bias,
    float* __restrict__ C, short* __restrict__ Ch, short* __restrict__ Cl,
    int M, int N, int K, int act) {
  __shared__ short Ash[128 * 40];
  __shared__ short Asl[128 * 40];
  __shared__ short Bsh[128 * 40];
  __shared__ short Bsl[128 * 40];
  int tid = threadIdx.x;
  int wave = tid >> 6, lane = tid & 63;
  int wm = wave & 1, wn = wave >> 1;
  int row0 = blockIdx.y * 128, col0 = blockIdx.x * 128;
  floatx4 acc[4][4] = {};
  int lm = lane & 15, lk = (lane >> 4) * 8;
  for (int k0 = 0; k0 < K; k0 += 32) {
    for (int c = tid; c < 512; c += 256) {
      int r = c >> 2, kc = (c & 3) * 8;
      int grow = row0 + r;
      short8 vh = {}, vl = {};
      if (grow < M) {
        vh = *(const short8*)&Ah[(size_t)grow * K + k0 + kc];
        vl = *(const short8*)&Al[(size_t)grow * K + k0 + kc];
      }
      *(short8*)&Ash[r * 40 + kc] = vh;
      *(short8*)&Asl[r * 40 + kc] = vl;
    }
    for (int c = tid; c < 512; c += 256) {
      int r = c >> 2, kc = (c & 3) * 8;
      int gn = col0 + r;
      short8 vh = {}, vl = {};
      if (gn < N) {
        vh = *(const short8*)&Wth[(size_t)gn * K + k0 + kc];
        vl = *(const short8*)&Wtl[(size_t)gn * K + k0 + kc];
      }
      *(short8*)&Bsh[r * 40 + kc] = vh;
      *(short8*)&Bsl[r * 40 + kc] = vl;
    }
    __syncthreads();
    short8 afh[4], afl[4], bfh[4], bfl[4];
#pragma unroll
    for (int mi = 0; mi < 4; ++mi) {
      int ro = (wm * 64 + mi * 16 + lm) * 40 + lk;
      afh[mi] = *(const short8*)&Ash[ro];
      afl[mi] = *(const short8*)&Asl[ro];
    }
#pragma unroll
    for (int ni = 0; ni < 4; ++ni) {
      int ro = (wn * 64 + ni * 16 + lm) * 40 + lk;
      bfh[ni] = *(const short8*)&Bsh[ro];
      bfl[ni] = *(const short8*)&Bsl[ro];
    }
#pragma unroll
    for (int mi = 0; mi < 4; ++mi)
#pragma unroll
      for (int ni = 0; ni < 4; ++ni) {
        acc[mi][ni] = __builtin_amdgcn_mfma_f32_16x16x32_bf16(afh[mi], bfh[ni], acc[mi][ni], 0, 0, 0);
        acc[mi][ni] = __builtin_amdgcn_mfma_f32_16x16x32_bf16(afh[mi], bfl[ni], acc[mi][ni], 0, 0, 0);
        acc[mi][ni] = __builtin_amdgcn_mfma_f32_16x16x32_bf16(afl[mi], bfh[ni], acc[mi][ni], 0, 0, 0);
      }
    __syncthreads();
  }
  int lr = (lane >> 4) * 4;
#pragma unroll
  for (int mi = 0; mi < 4; ++mi)
#pragma unroll
    for (int ni = 0; ni < 4; ++ni) {
      int colg = col0 + wn * 64 + ni * 16 + lm;
      if (colg >= N) continue;
      float bv = bias ? bias[colg] : 0.f;
#pragma unroll
      for (int r = 0; r < 4; ++r) {
        int rowg = row0 + wm * 64 + mi * 16 + lr + r;
        if (rowg >= M) continue;
        float v = acc[mi][ni][r] + bv;
        if (act == 1) v = fmaxf(v, 0.f);
        C[(size_t)rowg * N + colg] = v;
        if (Ch) {
          short hi, lo;
          f2b2(v, hi, lo);
          Ch[(size_t)rowg * N + colg] = hi;
          Cl[(size_t)rowg * N + colg] = lo;
        }
      }
    }
}

// Thin GEMM (small M): one block per row.
__global__ __launch_bounds__(256) void rowgemm_kernel(
    const float* __restrict__ A, const float* __restrict__ W, const float* __restrict__ bias,
    float* __restrict__ C, int N, int K, int act) {
  __shared__ float a[512];
  int row = blockIdx.x;
  for (int k = threadIdx.x; k < K; k += 256) a[k] = A[(size_t)row * K + k];
  __syncthreads();
  for (int c = threadIdx.x; c < N; c += 256) {
    float s = 0.f;
    for (int k = 0; k < K; k += 4) {
      float4 av = *(const float4*)&a[k];
      s += av.x * W[(size_t)k * N + c];
      s += av.y * W[(size_t)(k + 1) * N + c];
      s += av.z * W[(size_t)(k + 2) * N + c];
      s += av.w * W[(size_t)(k + 3) * N + c];
    }
    float v = s + (bias ? bias[c] : 0.f);
    if (act == 1) v = fmaxf(v, 0.f);
    C[(size_t)row * N + c] = v;
  }
}

// one wave per output element (for very small M*N)
__global__ void wavedot_gemm_kernel(const float* __restrict__ A, const float* __restrict__ W,
                                    const float* __restrict__ bias, float* __restrict__ C,
                                    int M, int N, int K, int act) {
  int wid = (blockIdx.x * blockDim.x + threadIdx.x) >> 6;
  int lane = threadIdx.x & 63;
  if (wid >= M * N) return;
  int row = wid / N, col = wid - row * N;
  const float* ar = A + (size_t)row * K;
  float s = 0.f;
  for (int k = lane; k < K; k += 64) s += ar[k] * W[(size_t)k * N + col];
  for (int off = 32; off; off >>= 1) s += __shfl_down(s, off, 64);
  if (lane == 0) {
    float v = s + (bias ? bias[col] : 0.f);
    if (act == 1) v = fmaxf(v, 0.f);
    C[(size_t)row * N + col] = v;
  }
}

// AB row r: [0..Hc) = xi@(Wt-Wb), [Hc..2Hc) = xi@Wb.  out = max_k relu(Ai + b + Bm[nbr]) [tanh]
__global__ void edge_agg_kernel(const float* __restrict__ AB, const float* __restrict__ bias,
                                const int* __restrict__ idx, int n, int Hc, int act,
                                float* __restrict__ out,
                                short* __restrict__ outh, short* __restrict__ outl) {
  int t = blockIdx.x * blockDim.x + threadIdx.x;
  if (t >= B_ * n * Hc) return;
  int r = t / Hc, h = t - r * Hc;
  int b = r / n;
  int s2 = 2 * Hc;
  float av = AB[(size_t)r * s2 + h] + bias[h];
  const int* ir = idx + (size_t)r * KNN_;
  int base = b * n;
  float m = -INFINITY;
  for (int k = 0; k < KNN_; ++k) {
    float v = av + AB[(size_t)(base + ir[k]) * s2 + Hc + h];
    v = fmaxf(v, 0.f);
    m = fmaxf(m, v);
  }
  if (act == 2) m = tanhf(m);
  out[t] = m;
  if (outh) {
    short hi, lo;
    f2b2(m, hi, lo);
    outh[t] = hi;
    outl[t] = lo;
  }
}

__global__ void bn_stats_kernel(const float* __restrict__ x, int M, float* __restrict__ mv) {
  int c = blockIdx.x;
  double s = 0.0, s2 = 0.0;
  for (int r = threadIdx.x; r < M; r += 256) {
    double v = (double)x[(size_t)r * H_ + c];
    s += v; s2 += v * v;
  }
  __shared__ double sh[256], sh2[256];
  sh[threadIdx.x] = s; sh2[threadIdx.x] = s2;
  __syncthreads();
  for (int o = 128; o; o >>= 1) {
    if (threadIdx.x < o) { sh[threadIdx.x] += sh[threadIdx.x + o]; sh2[threadIdx.x] += sh2[threadIdx.x + o]; }
    __syncthreads();
  }
  if (threadIdx.x == 0) {
    double mean = sh[0] / M;
    double var = sh2[0] / M - mean * mean;
    mv[c] = (float)mean;
    mv[H_ + c] = (float)var;
  }
}

__global__ void bn_apply_kernel(const float* __restrict__ x, const float* __restrict__ mv,
                                const float* __restrict__ g, const float* __restrict__ bb,
                                int M, float* __restrict__ out) {
  int t = blockIdx.x * blockDim.x + threadIdx.x;
  if (t >= M * H_) return;
  int h = t & (H_ - 1);
  float mean = mv[h], var = mv[H_ + h];
  float v = (x[t] - mean) * (1.f / sqrtf(var + 1e-5f)) * g[h] + bb[h];
  out[t] = fmaxf(v, 0.f);
}

// one wave per row: y[r] = dot(x[r,:K], w) [+bias] [relu]
__global__ void rowdot_kernel(const float* __restrict__ x, const float* __restrict__ w,
                              int M, int K, const float* __restrict__ bias, int act,
                              float* __restrict__ y) {
  int wid = (blockIdx.x * blockDim.x + threadIdx.x) >> 6;
  int lane = threadIdx.x & 63;
  if (wid >= M) return;
  const float* xr = x + (size_t)wid * K;
  float s = 0.f;
  for (int k = lane; k < K; k += 64) s += xr[k] * w[k];
  for (int off = 32; off; off >>= 1) s += __shfl_down(s, off, 64);
  if (lane == 0) {
    float v = s + (bias ? bias[0] : 0.f);
    if (act == 1) v = fmaxf(v, 0.f);
    y[wid] = v;
  }
}

// ---------------- fused SAG pool: rowdot + gcn score + topk + gather (block per graph) ----------------
__global__ __launch_bounds__(256) void sag_kernel(
    const float* __restrict__ h, const float* __restrict__ adj_in, int n, int k,
    const float* __restrict__ pw, const float* __restrict__ pb,
    int* __restrict__ perm, float* __restrict__ xp, float* __restrict__ adjp) {
  __shared__ float ys[40], dinv[40], sc[40], topv[40];
  __shared__ int locs[40];
  int b = blockIdx.x;
  int wave = threadIdx.x >> 6, lane = threadIdx.x & 63;
  // rowdot: y[i] = h[b,i,:] . pw
  for (int i = wave; i < n; i += 4) {
    const float* xr = h + (size_t)(b * n + i) * H_;
    float s = 0.f;
    for (int kk = lane; kk < H_; kk += 64) s += xr[kk] * pw[kk];
    for (int off = 32; off; off >>= 1) s += __shfl_down(s, off, 64);
    if (lane == 0) ys[i] = s;
  }
  __syncthreads();
  int i = threadIdx.x;
  if (i < n) {
    const float* ar = adj_in + ((size_t)b * n + i) * n;
    float sum = 1.f;
    for (int j = 0; j < n; ++j) sum += ar[j];
    dinv[i] = 1.f / sqrtf(sum);
  }
  __syncthreads();
  if (i < n) {
    const float* ar = adj_in + ((size_t)b * n + i) * n;
    float acc = 0.f;
    for (int j = 0; j < n; ++j) {
      float a = ar[j] + (i == j ? 1.f : 0.f);
      acc += a * dinv[j] * ys[j];
    }
    sc[i] = dinv[i] * acc + pb[0];
  }
  __syncthreads();
  if (wave == 0) {
    float cur = (lane < n) ? sc[lane] : -INFINITY;
    for (int t = 0; t < k; ++t) {
      float rv = cur;
      int rj = (lane < n) ? lane : (1 << 20);
      wave_argmax64(rv, rj);
      if (lane == 0) { topv[t] = rv; locs[t] = rj; perm[b * k + t] = b * n + rj; }
      if (lane == rj) cur = -INFINITY;
    }
  }
  __syncthreads();
  for (int e = threadIdx.x; e < k * H_; e += 256) {
    int r = e >> 8, hh = e & 255;
    xp[((size_t)b * k + r) * H_ + hh] =
        h[((size_t)(b * n + locs[r])) * H_ + hh] * tanhf(topv[r]);
  }
  if (adjp) {
    for (int e = threadIdx.x; e < k * k; e += 256) {
      int t1 = e / k, t2 = e - t1 * k;
      adjp[(size_t)b * k * k + e] = adj_in[((size_t)b * n + locs[t1]) * n + locs[t2]];
    }
  }
}

// dst[i1[i2[r]] or i1[r]] = src[r]; fp32 + split-bf16 (all pre-zeroed)
__global__ void scatter_kernel(const float* __restrict__ src, const int* __restrict__ i1,
                               const int* __restrict__ i2, int rows,
                               float* __restrict__ dst,
                               short* __restrict__ dsth, short* __restrict__ dstl) {
  int t = blockIdx.x * blockDim.x + threadIdx.x;
  if (t >= rows * H_) return;
  int r = t / H_, h = t - r * H_;
  int tgt = i2 ? i1[i2[r]] : i1[r];
  float v = src[t];
  dst[(size_t)tgt * H_ + h] = v;
  short hi, lo;
  f2b2(v, hi, lo);
  dsth[(size_t)tgt * H_ + h] = hi;
  dstl[(size_t)tgt * H_ + h] = lo;
}

__global__ void gtpred_kernel(const float* __restrict__ deg, const float* __restrict__ xdeg,
                              const int* __restrict__ perm, int M,
                              float* __restrict__ gt, float* __restrict__ pred) {
  int t = blockIdx.x * blockDim.x + threadIdx.x;
  if (t >= M) return;
  int p = perm[t];
  gt[t] = deg[p];
  pred[t] = xdeg[p];
}

__global__ void readout_kernel(const float* __restrict__ xp, int k, int acc, float* __restrict__ z) {
  int t = blockIdx.x * blockDim.x + threadIdx.x;
  if (t >= B_ * H_) return;
  int b = t / H_, h = t - b * H_;
  float mx = -INFINITY, sm = 0.f;
  for (int tt = 0; tt < k; ++tt) {
    float v = xp[((size_t)b * k + tt) * H_ + h];
    mx = fmaxf(mx, v);
    sm += v;
  }
  float* zb = z + (size_t)b * 2 * H_;
  float mean = sm / (float)k;
  if (acc) { zb[h] += mx; zb[H_ + h] += mean; }
  else     { zb[h] = mx;  zb[H_ + h] = mean; }
}

__global__ void softmax2_kernel(const float* __restrict__ logits, float* __restrict__ probs) {
  int b = blockIdx.x * blockDim.x + threadIdx.x;
  if (b >= B_) return;
  float a = logits[2 * b], c = logits[2 * b + 1];
  float m = fmaxf(a, c);
  float ea = expf(a - m), ec = expf(c - m);
  float inv = 1.f / (ea + ec);
  probs[2 * b] = ea * inv;
  probs[2 * b + 1] = ec * inv;
}

extern "C" void kernel_launch(void* const* d_in, const int* in_sizes, int n_in,
                              void* d_out, int out_size, void* d_ws, size_t ws_size,
                              hipStream_t stream) {
  auto in = [&](int i) { return (const float*)d_in[i]; };
  const float* x      = in(0);
  const float* adj    = in(1);
  const float* w_mlp1 = in(2);  const float* b_mlp1 = in(3);
  const float* w_mlp2 = in(4);  const float* b_mlp2 = in(5);
  const float* w_mlp3 = in(6);  const float* b_mlp3 = in(7);
  const float* w_mlp6 = in(8);  const float* b_mlp6 = in(9);
  const float* bn1_g = in(10);  const float* bn1_b = in(11);
  const float* bn2_g = in(12);  const float* bn2_b = in(13);
  const float* bn3_g = in(14);  const float* bn3_b = in(15);
  const float* p1_w = in(16);   const float* p1_b = in(17);
  const float* p2_w = in(18);   const float* p2_b = in(19);
  const float* p3_w = in(20);   const float* p3_b = in(21);
  const float* lin1_w = in(22); const float* lin1_b = in(23);
  const float* lin2_w = in(24); const float* lin2_b = in(25);
  const float* lin3_w = in(26); const float* lin3_b = in(27);
  const float* lin4_w = in(28); const float* lin4_b = in(29);
  const float* lin5_w = in(30); const float* lin5_b = in(31);
  const float* lin6_w = in(32); const float* lin6_b = in(33);

  float* out = (float*)d_out;
  float* out_probs = out;                      // 128*2
  float* out_dec1  = out_probs + 256;          // 4992*39
  float* out_dec2  = out_dec1 + 4992 * 39;
  float* out_dec3  = out_dec2 + 4992 * 39;
  float* out_gt1   = out_dec3 + 4992 * 39;     // 4096
  float* out_pred1 = out_gt1 + 4096;           // 4096
  float* out_gt2   = out_pred1 + 4096;         // 3328
  float* out_pred2 = out_gt2 + 3328;
  float* out_gt3   = out_pred2 + 3328;         // 2688
  float* out_pred3 = out_gt3 + 2688;

  char* base = (char*)d_ws;
  size_t off = 0;
  auto allocf = [&](size_t n) -> float* {
    float* p = (float*)(base + off);
    off += ((n * sizeof(float) + 255) & ~(size_t)255);
    return p;
  };
  auto alloci = [&](size_t n) -> int* {
    int* p = (int*)(base + off);
    off += ((n * sizeof(int) + 255) & ~(size_t)255);
    return p;
  };
  auto allocs = [&](size_t n) -> short* {
    short* p = (short*)(base + off);
    off += ((n * sizeof(short) + 255) & ~(size_t)255);
    return p;
  };

  float* wcat1 = allocf(39 * 512);
  float* wcat2 = allocf(256 * 512);
  float* wcat3 = allocf(256 * 512);
  short* wcat2t_h = allocs(512 * 256); short* wcat2t_l = allocs(512 * 256);
  short* wcat3t_h = allocs(512 * 256); short* wcat3t_l = allocs(512 * 256);
  short* wcat6t_h = allocs(78 * 256);  short* wcat6t_l = allocs(78 * 256);
  short* lin4t_h  = allocs(256 * 256); short* lin4t_l  = allocs(256 * 256);
  short* lin5t_h  = allocs(128 * 256); short* lin5t_l  = allocs(128 * 256);
  float* deg   = allocf(4992);
  float* xdeg  = allocf(4992);
  int*   idxb  = alloci(4992 * KNN_);
  float* AB    = allocf((size_t)4992 * 512);
  float* t1    = allocf((size_t)4992 * 256);
  float* t2    = allocf((size_t)4992 * 256);
  float* hbuf  = allocf((size_t)4992 * 256);
  float* xp    = allocf((size_t)4096 * 256);
  size_t ms0 = off;                             // contiguous memset region start
  float* xout  = allocf((size_t)4992 * 256);
  short* xout_h = allocs((size_t)4992 * 256);
  short* xout_l = allocs((size_t)4992 * 256);
  size_t msz = off - ms0;                       // one memset covers xout + both bf16 copies
  short* t1_h   = allocs((size_t)4992 * 256); short* t1_l   = allocs((size_t)4992 * 256);
  short* t2_h   = allocs((size_t)4992 * 256); short* t2_l   = allocs((size_t)4992 * 256);
  float* adj1  = allocf(128 * 32 * 32);
  float* adj2  = allocf(128 * 26 * 26);
  float* stats = allocf(512);
  int* perm1 = alloci(4096); int* perm2 = alloci(3328); int* perm3 = alloci(2688);
  float* z  = allocf(128 * 512);
  float* z1 = allocf(128 * 256);
  float* z2 = allocf(128 * 128);
  float* logits = allocf(256);
  if (off > ws_size) return;

  auto glds = [](int F) -> size_t {
    int S = (F & 3) ? F + 5 : F + 4;
    return (size_t)(40 * S) * sizeof(float);
  };

  // fp32 trunk edge conv (feeds top-k; exact)
  auto edge_conv = [&](const float* xin, int n, int F, const float* wcat, const float* bias,
                       int Hout, float* outbuf) {
    int M = B_ * n;
    gram_knn_kernel<<<dim3(B_, GSPLIT), 256, glds(F), stream>>>(xin, n, F, idxb);
    dim3 gg(cdiv(2 * Hout, BN), cdiv(M, BM));
    gemm_kernel<<<gg, 256, 0, stream>>>(xin, wcat, nullptr, AB, M, 2 * Hout, F, 0);
    edge_agg_kernel<<<cdiv(M * Hout, 256), 256, 0, stream>>>(AB, bias, idxb, n, Hout, 0, outbuf, nullptr, nullptr);
  };
  // split-bf16 decoder edge conv
  auto edge_conv_bf = [&](const float* xin, const short* xh, const short* xl,
                          const short* wth, const short* wtl,
                          const float* bias, int Hout, int act,
                          float* outbuf, short* outh, short* outl) {
    int M = 4992, F = 256;
    gram_knn_kernel<<<dim3(B_, GSPLIT), 256, glds(F), stream>>>(xin, N_, F, idxb);
    dim3 gg(cdiv(2 * Hout, 128), cdiv(M, 128));
    mfma_gemm_split_kernel<<<gg, 256, 0, stream>>>(xh, xl, wth, wtl, nullptr, AB, nullptr, nullptr,
                                                   M, 2 * Hout, F, 0);
    edge_agg_kernel<<<cdiv(M * Hout, 256), 256, 0, stream>>>(AB, bias, idxb, N_, Hout, act, outbuf, outh, outl);
  };
  auto decoder = [&](const float* xin, const short* xh, const short* xl, float* decout) {
    edge_conv_bf(xin, xh, xl, wcat3t_h, wcat3t_l, b_mlp3, H_, 2, t1, t1_h, t1_l);
    edge_conv_bf(t1, t1_h, t1_l, wcat2t_h, wcat2t_l, b_mlp2, H_, 2, t2, t2_h, t2_l);
    edge_conv_bf(t2, t2_h, t2_l, wcat6t_h, wcat6t_l, b_mlp6, N_, 0, decout, nullptr, nullptr);
  };

  // ---- one-shot prep ----
  prep_kernel<<<dim3(512, 7), 256, 0, stream>>>(
      w_mlp1, w_mlp2, w_mlp3, w_mlp6, lin4_w, lin5_w, adj,
      wcat1, wcat2, wcat3,
      wcat2t_h, wcat2t_l, wcat3t_h, wcat3t_l, wcat6t_h, wcat6t_l,
      lin4t_h, lin4t_l, lin5t_h, lin5t_l, deg);

  // ---- level 1 ----
  edge_conv(x, N_, N_, wcat1, b_mlp1, H_, t1);
  bn_stats_kernel<<<H_, 256, 0, stream>>>(t1, 4992, stats);
  bn_apply_kernel<<<cdiv(4992 * 256, 256), 256, 0, stream>>>(t1, stats, bn1_g, bn1_b, 4992, hbuf);
  sag_kernel<<<B_, 256, 0, stream>>>(hbuf, adj, N_, K1_, p1_w, p1_b, perm1, xp, adj1);
  hipMemsetAsync(xout, 0, msz, stream);
  scatter_kernel<<<cdiv(4096 * 256, 256), 256, 0, stream>>>(xp, perm1, nullptr, 4096, xout, xout_h, xout_l);
  {
    dim3 g4(2, 39);
    mfma_gemm_split_kernel<<<g4, 256, 0, stream>>>(xout_h, xout_l, lin4t_h, lin4t_l, lin4_b,
                                                   t1, t1_h, t1_l, 4992, 256, 256, 1);
    dim3 g5(1, 39);
    mfma_gemm_split_kernel<<<g5, 256, 0, stream>>>(t1_h, t1_l, lin5t_h, lin5t_l, lin5_b,
                                                   t2, nullptr, nullptr, 4992, 128, 256, 1);
  }
  rowdot_kernel<<<cdiv(4992 * 64, 256), 256, 0, stream>>>(t2, lin6_w, 4992, 128, lin6_b, 1, xdeg);
  gtpred_kernel<<<cdiv(4096, 256), 256, 0, stream>>>(deg, xdeg, perm1, 4096, out_gt1, out_pred1);
  readout_kernel<<<cdiv(128 * 256, 256), 256, 0, stream>>>(xp, K1_, 0, z);
  decoder(xout, xout_h, xout_l, out_dec1);

  // ---- level 2 ----
  edge_conv(xp, K1_, H_, wcat2, b_mlp2, H_, t1);
  bn_stats_kernel<<<H_, 256, 0, stream>>>(t1, 4096, stats);
  bn_apply_kernel<<<cdiv(4096 * 256, 256), 256, 0, stream>>>(t1, stats, bn2_g, bn2_b, 4096, hbuf);
  sag_kernel<<<B_, 256, 0, stream>>>(hbuf, adj1, K1_, K2_, p2_w, p2_b, perm2, xp, adj2);
  hipMemsetAsync(xout, 0, msz, stream);
  scatter_kernel<<<cdiv(3328 * 256, 256), 256, 0, stream>>>(xp, perm1, perm2, 3328, xout, xout_h, xout_l);
  gtpred_kernel<<<cdiv(3328, 256), 256, 0, stream>>>(deg, xdeg, perm2, 3328, out_gt2, out_pred2);
  readout_kernel<<<cdiv(128 * 256, 256), 256, 0, stream>>>(xp, K2_, 1, z);
  decoder(xout, xout_h, xout_l, out_dec2);

  // ---- level 3 ----
  edge_conv(xp, K2_, H_, wcat3, b_mlp3, H_, t1);
  bn_stats_kernel<<<H_, 256, 0, stream>>>(t1, 3328, stats);
  bn_apply_kernel<<<cdiv(3328 * 256, 256), 256, 0, stream>>>(t1, stats, bn3_g, bn3_b, 3328, hbuf);
  sag_kernel<<<B_, 256, 0, stream>>>(hbuf, adj2, K2_, K3_, p3_w, p3_b, perm3, xp, nullptr);
  hipMemsetAsync(xout, 0, msz, stream);
  scatter_kernel<<<cdiv(2688 * 256, 256), 256, 0, stream>>>(xp, perm2, perm3, 2688, xout, xout_h, xout_l);
  gtpred_kernel<<<cdiv(2688, 256), 256, 0, stream>>>(deg, xdeg, perm3, 2688, out_gt3, out_pred3);
  readout_kernel<<<cdiv(128 * 256, 256), 256, 0, stream>>>(xp, K3_, 1, z);
  decoder(xout, xout_h, xout_l, out_dec3);

  // ---- classifier head (thin: M=128) ----
  rowgemm_kernel<<<128, 256, 0, stream>>>(z, lin1_w, lin1_b, z1, 256, 512, 1);
  rowgemm_kernel<<<128, 256, 0, stream>>>(z1, lin2_w, lin2_b, z2, 128, 256, 1);
  wavedot_gemm_kernel<<<cdiv(128 * 2 * 64, 256), 256, 0, stream>>>(z2, lin3_w, lin3_b, logits, 128, 2, 128, 0);
  softmax2_kernel<<<1, 128, 0, stream>>>(logits, out_probs);
}

// Round 8
// 1245.466 us; speedup vs baseline: 1.3921x; 1.0046x over previous
//
#include <hip/hip_runtime.h>
#include <cmath>

#define B_   128
#define N_   39
#define KNN_ 10
#define H_   256
#define K1_  32
#define K2_  26
#define K3_  21

static inline int cdiv(int a, int b) { return (a + b - 1) / b; }

typedef __attribute__((ext_vector_type(8))) short short8;
typedef __attribute__((ext_vector_type(4))) float floatx4;

__device__ inline short f2b(float f) {   // fp32 -> bf16 RNE
  unsigned u = __float_as_uint(f);
  u += 0x7fff + ((u >> 16) & 1);
  return (short)(u >> 16);
}
__device__ inline float b2f(short h) {
  return __uint_as_float(((unsigned)(unsigned short)h) << 16);
}
__device__ inline void f2b2(float v, short& hi, short& lo) {  // split: v ~= hi + lo
  hi = f2b(v);
  lo = f2b(v - b2f(hi));
}

// ---------- wave-wide argmax/argmin (64 lanes), ties -> lowest index ----------
__device__ inline void wave_argmax64(float& v, int& j) {
#pragma unroll
  for (int off = 32; off; off >>= 1) {
    float ov = __shfl_down(v, off, 64);
    int   oj = __shfl_down(j, off, 64);
    if (ov > v || (ov == v && oj < j)) { v = ov; j = oj; }
  }
  v = __shfl(v, 0, 64);
  j = __shfl(j, 0, 64);
}
__device__ inline void wave_argmin64(float& v, int& j) {
#pragma unroll
  for (int off = 32; off; off >>= 1) {
    float ov = __shfl_down(v, off, 64);
    int   oj = __shfl_down(j, off, 64);
    if (ov < v || (ov == v && oj < j)) { v = ov; j = oj; }
  }
  v = __shfl(v, 0, 64);
  j = __shfl(j, 0, 64);
}

// ---------------- one-shot weight prep + degree (7 tasks on blockIdx.y) ----------------
__global__ void prep_kernel(const float* __restrict__ w1, const float* __restrict__ w2,
                            const float* __restrict__ w3, const float* __restrict__ w6,
                            const float* __restrict__ l4, const float* __restrict__ l5,
                            const float* __restrict__ adj,
                            float* __restrict__ wcat1, float* __restrict__ wcat2,
                            float* __restrict__ wcat3,
                            short* __restrict__ w2h, short* __restrict__ w2l,
                            short* __restrict__ w3h, short* __restrict__ w3l,
                            short* __restrict__ w6h, short* __restrict__ w6l,
                            short* __restrict__ l4h, short* __restrict__ l4l,
                            short* __restrict__ l5h, short* __restrict__ l5l,
                            float* __restrict__ deg) {
  int task = blockIdx.y;
  int t = blockIdx.x * 256 + threadIdx.x;
  if (task == 0) {                        // wcat1 fp32 only (F=39, Hc=256)
    if (t >= 39 * 512) return;
    int k = t >> 9, c = t & 511;
    wcat1[t] = (c < 256) ? w1[k * 256 + c] - w1[(39 + k) * 256 + c]
                         : w1[(39 + k) * 256 + (c - 256)];
  } else if (task == 1) {                 // wcat2 fp32 + splitT (F=256, Hc=256)
    if (t >= 256 * 512) return;
    int k = t >> 9, c = t & 511;
    float v = (c < 256) ? w2[k * 256 + c] - w2[(256 + k) * 256 + c]
                        : w2[(256 + k) * 256 + (c - 256)];
    wcat2[t] = v;
    short hi, lo; f2b2(v, hi, lo);
    w2h[(size_t)c * 256 + k] = hi; w2l[(size_t)c * 256 + k] = lo;
  } else if (task == 2) {                 // wcat3 fp32 + splitT
    if (t >= 256 * 512) return;
    int k = t >> 9, c = t & 511;
    float v = (c < 256) ? w3[k * 256 + c] - w3[(256 + k) * 256 + c]
                        : w3[(256 + k) * 256 + (c - 256)];
    wcat3[t] = v;
    short hi, lo; f2b2(v, hi, lo);
    w3h[(size_t)c * 256 + k] = hi; w3l[(size_t)c * 256 + k] = lo;
  } else if (task == 3) {                 // wcat6 splitT only (F=256, Hc=39)
    if (t >= 256 * 78) return;
    int k = t / 78, c = t - k * 78;
    float v = (c < 39) ? w6[k * 39 + c] - w6[(256 + k) * 39 + c]
                       : w6[(256 + k) * 39 + (c - 39)];
    short hi, lo; f2b2(v, hi, lo);
    w6h[(size_t)c * 256 + k] = hi; w6l[(size_t)c * 256 + k] = lo;
  } else if (task == 4) {                 // lin4 splitT (256 x 256)
    if (t >= 256 * 256) return;
    int k = t >> 8, n = t & 255;
    short hi, lo; f2b2(l4[t], hi, lo);
    l4h[(size_t)n * 256 + k] = hi; l4l[(size_t)n * 256 + k] = lo;
  } else if (task == 5) {                 // lin5 splitT (256 x 128)
    if (t >= 256 * 128) return;
    int k = t >> 7, n = t & 127;
    short hi, lo; f2b2(l5[t], hi, lo);
    l5h[(size_t)n * 256 + k] = hi; l5l[(size_t)n * 256 + k] = lo;
  } else {                                // degree
    if (t >= B_ * N_) return;
    const float* row = adj + (size_t)t * N_;
    float s = 0.f;
    for (int j = 0; j < N_; ++j) s += row[j];
    deg[t] = s;
  }
}

// ---------------- direct KNN, no LDS: one wave per output row ----------------
// lane j: dot = x_i . x_j and sq = |x_j|^2 straight from global (L1/L2-hot);
// |x_i|^2 via shfl from lane i. Ties -> lowest index (stable like lax.top_k).
__global__ __launch_bounds__(256) void knn_direct_kernel(const float* __restrict__ x,
                                                         int n, int F, int M,
                                                         int* __restrict__ idx) {
  int w = (blockIdx.x * blockDim.x + threadIdx.x) >> 6;
  int lane = threadIdx.x & 63;
  if (w >= M) return;
  int b = w / n, i = w - b * n;
  const float* xb = x + (size_t)b * n * F;
  int jr = (lane < n) ? lane : 0;
  const float* xj = xb + (size_t)jr * F;
  const float* xi = xb + (size_t)i * F;
  float dot, sq;
  if ((F & 3) == 0) {
    float d0 = 0.f, d1 = 0.f, s0 = 0.f, s1 = 0.f;
    for (int f = 0; f < F; f += 8) {
      float4 a0 = *(const float4*)&xi[f];
      float4 b0 = *(const float4*)&xj[f];
      float4 a1 = *(const float4*)&xi[f + 4];
      float4 b1 = *(const float4*)&xj[f + 4];
      d0 += a0.x * b0.x + a0.y * b0.y + a0.z * b0.z + a0.w * b0.w;
      s0 += b0.x * b0.x + b0.y * b0.y + b0.z * b0.z + b0.w * b0.w;
      d1 += a1.x * b1.x + a1.y * b1.y + a1.z * b1.z + a1.w * b1.w;
      s1 += b1.x * b1.x + b1.y * b1.y + b1.z * b1.z + b1.w * b1.w;
    }
    dot = d0 + d1; sq = s0 + s1;
  } else {
    float d0 = 0.f, s0 = 0.f;
    for (int f = 0; f < F; ++f) {
      float a = xi[f], bv = xj[f];
      d0 += a * bv;
      s0 += bv * bv;
    }
    dot = d0; sq = s0;
  }
  float sqi = __shfl(sq, i, 64);
  float d = (lane < n) ? (sqi + sq - 2.f * dot) : INFINITY;
  int* outp = idx + (size_t)w * KNN_;
  for (int kk = 0; kk < KNN_; ++kk) {
    float rv = d;
    int rj = (lane < n) ? lane : (1 << 20);
    wave_argmin64(rv, rj);
    if (lane == 0) outp[kk] = rj;
    if (lane == rj) d = INFINITY;
  }
}

// ---------------- fp32 trunk GEMM: 64x64 tile, register-staged pipeline ----------------
#define BM 64
#define BN 64
#define BK 16
__global__ __launch_bounds__(256) void gemm_kernel(
    const float* __restrict__ A, const float* __restrict__ W, const float* __restrict__ bias,
    float* __restrict__ C, int M, int N, int K, int act) {
  __shared__ float As[BK][BM + 4];
  __shared__ float Bs[BK][BN + 4];
  int tid = threadIdx.x;
  int tx = tid & 15, ty = tid >> 4;
  int row0 = blockIdx.y * BM, col0 = blockIdx.x * BN;
  float c[4][4] = {};
  float ra[4], rb[4];
#pragma unroll
  for (int v = 0; v < 4; ++v) {
    int e = tid + v * 256;
    int m = e >> 4, kk = e & 15;
    int row = row0 + m;
    ra[v] = (row < M && kk < K) ? A[(size_t)row * K + kk] : 0.f;
    int kk2 = e >> 6, nn = e & 63;
    int col = col0 + nn;
    rb[v] = (kk2 < K && col < N) ? W[(size_t)kk2 * N + col] : 0.f;
  }
  for (int k0 = 0; k0 < K; k0 += BK) {
#pragma unroll
    for (int v = 0; v < 4; ++v) {
      int e = tid + v * 256;
      As[e & 15][e >> 4] = ra[v];
      Bs[e >> 6][e & 63] = rb[v];
    }
    __syncthreads();
    int k1 = k0 + BK;
    if (k1 < K) {
#pragma unroll
      for (int v = 0; v < 4; ++v) {
        int e = tid + v * 256;
        int m = e >> 4, kk = e & 15;
        int row = row0 + m, k = k1 + kk;
        ra[v] = (row < M && k < K) ? A[(size_t)row * K + k] : 0.f;
        int kk2 = e >> 6, nn = e & 63;
        int k2 = k1 + kk2, col = col0 + nn;
        rb[v] = (k2 < K && col < N) ? W[(size_t)k2 * N + col] : 0.f;
      }
    }
#pragma unroll
    for (int kk = 0; kk < BK; ++kk) {
      float4 av = *(const float4*)&As[kk][ty * 4];
      float4 bv = *(const float4*)&Bs[kk][tx * 4];
      float a[4] = {av.x, av.y, av.z, av.w};
      float b[4] = {bv.x, bv.y, bv.z, bv.w};
#pragma unroll
      for (int i2 = 0; i2 < 4; ++i2)
#pragma unroll
        for (int j = 0; j < 4; ++j) c[i2][j] += a[i2] * b[j];
    }
    __syncthreads();
  }
#pragma unroll
  for (int i2 = 0; i2 < 4; ++i2) {
    int row = row0 + ty * 4 + i2;
    if (row >= M) continue;
#pragma unroll
    for (int j = 0; j < 4; ++j) {
      int col = col0 + tx * 4 + j;
      if (col >= N) continue;
      float v = c[i2][j] + (bias ? bias[col] : 0.f);
      if (act == 1) v = fmaxf(v, 0.f);
      C[(size_t)row * N + col] = v;
    }
  }
}

// ------------- split-bf16 3-pass MFMA GEMM (near-fp32 accuracy, ~2^-16 rel) -------------
__global__ __launch_bounds__(256) void mfma_gemm_split_kernel(
    const short* __restrict__ Ah, const short* __restrict__ Al,
    const short* __restrict__ Wth, const short* __restrict__ Wtl,
    const float* __restrict__ bias,
    float* __restrict__ C, short* __restrict__ Ch, short* __restrict__ Cl,
    int M, int N, int K, int act) {
  __shared__ short Ash[128 * 40];
  __shared__ short Asl[128 * 40];
  __shared__ short Bsh[128 * 40];
  __shared__ short Bsl[128 * 40];
  int tid = threadIdx.x;
  int wave = tid >> 6, lane = tid & 63;
  int wm = wave & 1, wn = wave >> 1;
  int row0 = blockIdx.y * 128, col0 = blockIdx.x * 128;
  floatx4 acc[4][4] = {};
  int lm = lane & 15, lk = (lane >> 4) * 8;
  for (int k0 = 0; k0 < K; k0 += 32) {
    for (int c = tid; c < 512; c += 256) {
      int r = c >> 2, kc = (c & 3) * 8;
      int grow = row0 + r;
      short8 vh = {}, vl = {};
      if (grow < M) {
        vh = *(const short8*)&Ah[(size_t)grow * K + k0 + kc];
        vl = *(const short8*)&Al[(size_t)grow * K + k0 + kc];
      }
      *(short8*)&Ash[r * 40 + kc] = vh;
      *(short8*)&Asl[r * 40 + kc] = vl;
    }
    for (int c = tid; c < 512; c += 256) {
      int r = c >> 2, kc = (c & 3) * 8;
      int gn = col0 + r;
      short8 vh = {}, vl = {};
      if (gn < N) {
        vh = *(const short8*)&Wth[(size_t)gn * K + k0 + kc];
        vl = *(const short8*)&Wtl[(size_t)gn * K + k0 + kc];
      }
      *(short8*)&Bsh[r * 40 + kc] = vh;
      *(short8*)&Bsl[r * 40 + kc] = vl;
    }
    __syncthreads();
    short8 afh[4], afl[4], bfh[4], bfl[4];
#pragma unroll
    for (int mi = 0; mi < 4; ++mi) {
      int ro = (wm * 64 + mi * 16 + lm) * 40 + lk;
      afh[mi] = *(const short8*)&Ash[ro];
      afl[mi] = *(const short8*)&Asl[ro];
    }
#pragma unroll
    for (int ni = 0; ni < 4; ++ni) {
      int ro = (wn * 64 + ni * 16 + lm) * 40 + lk;
      bfh[ni] = *(const short8*)&Bsh[ro];
      bfl[ni] = *(const short8*)&Bsl[ro];
    }
#pragma unroll
    for (int mi = 0; mi < 4; ++mi)
#pragma unroll
      for (int ni = 0; ni < 4; ++ni) {
        acc[mi][ni] = __builtin_amdgcn_mfma_f32_16x16x32_bf16(afh[mi], bfh[ni], acc[mi][ni], 0, 0, 0);
        acc[mi][ni] = __builtin_amdgcn_mfma_f32_16x16x32_bf16(afh[mi], bfl[ni], acc[mi][ni], 0, 0, 0);
        acc[mi][ni] = __builtin_amdgcn_mfma_f32_16x16x32_bf16(afl[mi], bfh[ni], acc[mi][ni], 0, 0, 0);
      }
    __syncthreads();
  }
  int lr = (lane >> 4) * 4;
#pragma unroll
  for (int mi = 0; mi < 4; ++mi)
#pragma unroll
    for (int ni = 0; ni < 4; ++ni) {
      int colg = col0 + wn * 64 + ni * 16 + lm;
      if (colg >= N) continue;
      float bv = bias ? bias[colg] : 0.f;
#pragma unroll
      for (int r = 0; r < 4; ++r) {
        int rowg = row0 + wm * 64 + mi * 16 + lr + r;
        if (rowg >= M) continue;
        float v = acc[mi][ni][r] + bv;
        if (act == 1) v = fmaxf(v, 0.f);
        C[(size_t)rowg * N + colg] = v;
        if (Ch) {
          short hi, lo;
          f2b2(v, hi, lo);
          Ch[(size_t)rowg * N + colg] = hi;
          Cl[(size_t)rowg * N + colg] = lo;
        }
      }
    }
}

// Thin GEMM (small M): one block per row.
__global__ __launch_bounds__(256) void rowgemm_kernel(
    const float* __restrict__ A, const float* __restrict__ W, const float* __restrict__ bias,
    float* __restrict__ C, int N, int K, int act) {
  __shared__ float a[512];
  int row = blockIdx.x;
  for (int k = threadIdx.x; k < K; k += 256) a[k] = A[(size_t)row * K + k];
  __syncthreads();
  for (int c = threadIdx.x; c < N; c += 256) {
    float s = 0.f;
    for (int k = 0; k < K; k += 4) {
      float4 av = *(const float4*)&a[k];
      s += av.x * W[(size_t)k * N + c];
      s += av.y * W[(size_t)(k + 1) * N + c];
      s += av.z * W[(size_t)(k + 2) * N + c];
      s += av.w * W[(size_t)(k + 3) * N + c];
    }
    float v = s + (bias ? bias[c] : 0.f);
    if (act == 1) v = fmaxf(v, 0.f);
    C[(size_t)row * N + c] = v;
  }
}

// one wave per output element (for very small M*N)
__global__ void wavedot_gemm_kernel(const float* __restrict__ A, const float* __restrict__ W,
                                    const float* __restrict__ bias, float* __restrict__ C,
                                    int M, int N, int K, int act) {
  int wid = (blockIdx.x * blockDim.x + threadIdx.x) >> 6;
  int lane = threadIdx.x & 63;
  if (wid >= M * N) return;
  int row = wid / N, col = wid - row * N;
  const float* ar = A + (size_t)row * K;
  float s = 0.f;
  for (int k = lane; k < K; k += 64) s += ar[k] * W[(size_t)k * N + col];
  for (int off = 32; off; off >>= 1) s += __shfl_down(s, off, 64);
  if (lane == 0) {
    float v = s + (bias ? bias[col] : 0.f);
    if (act == 1) v = fmaxf(v, 0.f);
    C[(size_t)row * N + col] = v;
  }
}

// AB row r: [0..Hc) = xi@(Wt-Wb), [Hc..2Hc) = xi@Wb.  out = max_k relu(Ai + b + Bm[nbr]) [tanh]
__global__ void edge_agg_kernel(const float* __restrict__ AB, const float* __restrict__ bias,
                                const int* __restrict__ idx, int n, int Hc, int act,
                                float* __restrict__ out,
                                short* __restrict__ outh, short* __restrict__ outl) {
  int t = blockIdx.x * blockDim.x + threadIdx.x;
  if (t >= B_ * n * Hc) return;
  int r = t / Hc, h = t - r * Hc;
  int b = r / n;
  int s2 = 2 * Hc;
  float av = AB[(size_t)r * s2 + h] + bias[h];
  const int* ir = idx + (size_t)r * KNN_;
  int base = b * n;
  float m = -INFINITY;
  for (int k = 0; k < KNN_; ++k) {
    float v = av + AB[(size_t)(base + ir[k]) * s2 + Hc + h];
    v = fmaxf(v, 0.f);
    m = fmaxf(m, v);
  }
  if (act == 2) m = tanhf(m);
  out[t] = m;
  if (outh) {
    short hi, lo;
    f2b2(m, hi, lo);
    outh[t] = hi;
    outl[t] = lo;
  }
}

__global__ void bn_stats_kernel(const float* __restrict__ x, int M, float* __restrict__ mv) {
  int c = blockIdx.x;
  double s = 0.0, s2 = 0.0;
  for (int r = threadIdx.x; r < M; r += 256) {
    double v = (double)x[(size_t)r * H_ + c];
    s += v; s2 += v * v;
  }
  __shared__ double sh[256], sh2[256];
  sh[threadIdx.x] = s; sh2[threadIdx.x] = s2;
  __syncthreads();
  for (int o = 128; o; o >>= 1) {
    if (threadIdx.x < o) { sh[threadIdx.x] += sh[threadIdx.x + o]; sh2[threadIdx.x] += sh2[threadIdx.x + o]; }
    __syncthreads();
  }
  if (threadIdx.x == 0) {
    double mean = sh[0] / M;
    double var = sh2[0] / M - mean * mean;
    mv[c] = (float)mean;
    mv[H_ + c] = (float)var;
  }
}

__global__ void bn_apply_kernel(const float* __restrict__ x, const float* __restrict__ mv,
                                const float* __restrict__ g, const float* __restrict__ bb,
                                int M, float* __restrict__ out) {
  int t = blockIdx.x * blockDim.x + threadIdx.x;
  if (t >= M * H_) return;
  int h = t & (H_ - 1);
  float mean = mv[h], var = mv[H_ + h];
  float v = (x[t] - mean) * (1.f / sqrtf(var + 1e-5f)) * g[h] + bb[h];
  out[t] = fmaxf(v, 0.f);
}

// one wave per row: y[r] = dot(x[r,:K], w) [+bias] [relu]
__global__ void rowdot_kernel(const float* __restrict__ x, const float* __restrict__ w,
                              int M, int K, const float* __restrict__ bias, int act,
                              float* __restrict__ y) {
  int wid = (blockIdx.x * blockDim.x + threadIdx.x) >> 6;
  int lane = threadIdx.x & 63;
  if (wid >= M) return;
  const float* xr = x + (size_t)wid * K;
  float s = 0.f;
  for (int k = lane; k < K; k += 64) s += xr[k] * w[k];
  for (int off = 32; off; off >>= 1) s += __shfl_down(s, off, 64);
  if (lane == 0) {
    float v = s + (bias ? bias[0] : 0.f);
    if (act == 1) v = fmaxf(v, 0.f);
    y[wid] = v;
  }
}

// ---------------- fused SAG pool: rowdot + gcn score + topk + gather (block per graph) ----------------
__global__ __launch_bounds__(256) void sag_kernel(
    const float* __restrict__ h, const float* __restrict__ adj_in, int n, int k,
    const float* __restrict__ pw, const float* __restrict__ pb,
    int* __restrict__ perm, float* __restrict__ xp, float* __restrict__ adjp) {
  __shared__ float ys[40], dinv[40], sc[40], topv[40];
  __shared__ int locs[40];
  int b = blockIdx.x;
  int wave = threadIdx.x >> 6, lane = threadIdx.x & 63;
  // rowdot: y[i] = h[b,i,:] . pw
  for (int i = wave; i < n; i += 4) {
    const float* xr = h + (size_t)(b * n + i) * H_;
    float s = 0.f;
    for (int kk = lane; kk < H_; kk += 64) s += xr[kk] * pw[kk];
    for (int off = 32; off; off >>= 1) s += __shfl_down(s, off, 64);
    if (lane == 0) ys[i] = s;
  }
  __syncthreads();
  int i = threadIdx.x;
  if (i < n) {
    const float* ar = adj_in + ((size_t)b * n + i) * n;
    float sum = 1.f;
    for (int j = 0; j < n; ++j) sum += ar[j];
    dinv[i] = 1.f / sqrtf(sum);
  }
  __syncthreads();
  if (i < n) {
    const float* ar = adj_in + ((size_t)b * n + i) * n;
    float acc = 0.f;
    for (int j = 0; j < n; ++j) {
      float a = ar[j] + (i == j ? 1.f : 0.f);
      acc += a * dinv[j] * ys[j];
    }
    sc[i] = dinv[i] * acc + pb[0];
  }
  __syncthreads();
  if (wave == 0) {
    float cur = (lane < n) ? sc[lane] : -INFINITY;
    for (int t = 0; t < k; ++t) {
      float rv = cur;
      int rj = (lane < n) ? lane : (1 << 20);
      wave_argmax64(rv, rj);
      if (lane == 0) { topv[t] = rv; locs[t] = rj; perm[b * k + t] = b * n + rj; }
      if (lane == rj) cur = -INFINITY;
    }
  }
  __syncthreads();
  for (int e = threadIdx.x; e < k * H_; e += 256) {
    int r = e >> 8, hh = e & 255;
    xp[((size_t)b * k + r) * H_ + hh] =
        h[((size_t)(b * n + locs[r])) * H_ + hh] * tanhf(topv[r]);
  }
  if (adjp) {
    for (int e = threadIdx.x; e < k * k; e += 256) {
      int t1 = e / k, t2 = e - t1 * k;
      adjp[(size_t)b * k * k + e] = adj_in[((size_t)b * n + locs[t1]) * n + locs[t2]];
    }
  }
}

// dst[i1[i2[r]] or i1[r]] = src[r]; fp32 + split-bf16 (all pre-zeroed)
__global__ void scatter_kernel(const float* __restrict__ src, const int* __restrict__ i1,
                               const int* __restrict__ i2, int rows,
                               float* __restrict__ dst,
                               short* __restrict__ dsth, short* __restrict__ dstl) {
  int t = blockIdx.x * blockDim.x + threadIdx.x;
  if (t >= rows * H_) return;
  int r = t / H_, h = t - r * H_;
  int tgt = i2 ? i1[i2[r]] : i1[r];
  float v = src[t];
  dst[(size_t)tgt * H_ + h] = v;
  short hi, lo;
  f2b2(v, hi, lo);
  dsth[(size_t)tgt * H_ + h] = hi;
  dstl[(size_t)tgt * H_ + h] = lo;
}

__global__ void gtpred_kernel(const float* __restrict__ deg, const float* __restrict__ xdeg,
                              const int* __restrict__ perm, int M,
                              float* __restrict__ gt, float* __restrict__ pred) {
  int t = blockIdx.x * blockDim.x + threadIdx.x;
  if (t >= M) return;
  int p = perm[t];
  gt[t] = deg[p];
  pred[t] = xdeg[p];
}

__global__ void readout_kernel(const float* __restrict__ xp, int k, int acc, float* __restrict__ z) {
  int t = blockIdx.x * blockDim.x + threadIdx.x;
  if (t >= B_ * H_) return;
  int b = t / H_, h = t - b * H_;
  float mx = -INFINITY, sm = 0.f;
  for (int tt = 0; tt < k; ++tt) {
    float v = xp[((size_t)b * k + tt) * H_ + h];
    mx = fmaxf(mx, v);
    sm += v;
  }
  float* zb = z + (size_t)b * 2 * H_;
  float mean = sm / (float)k;
  if (acc) { zb[h] += mx; zb[H_ + h] += mean; }
  else     { zb[h] = mx;  zb[H_ + h] = mean; }
}

__global__ void softmax2_kernel(const float* __restrict__ logits, float* __restrict__ probs) {
  int b = blockIdx.x * blockDim.x + threadIdx.x;
  if (b >= B_) return;
  float a = logits[2 * b], c = logits[2 * b + 1];
  float m = fmaxf(a, c);
  float ea = expf(a - m), ec = expf(c - m);
  float inv = 1.f / (ea + ec);
  probs[2 * b] = ea * inv;
  probs[2 * b + 1] = ec * inv;
}

extern "C" void kernel_launch(void* const* d_in, const int* in_sizes, int n_in,
                              void* d_out, int out_size, void* d_ws, size_t ws_size,
                              hipStream_t stream) {
  auto in = [&](int i) { return (const float*)d_in[i]; };
  const float* x      = in(0);
  const float* adj    = in(1);
  const float* w_mlp1 = in(2);  const float* b_mlp1 = in(3);
  const float* w_mlp2 = in(4);  const float* b_mlp2 = in(5);
  const float* w_mlp3 = in(6);  const float* b_mlp3 = in(7);
  const float* w_mlp6 = in(8);  const float* b_mlp6 = in(9);
  const float* bn1_g = in(10);  const float* bn1_b = in(11);
  const float* bn2_g = in(12);  const float* bn2_b = in(13);
  const float* bn3_g = in(14);  const float* bn3_b = in(15);
  const float* p1_w = in(16);   const float* p1_b = in(17);
  const float* p2_w = in(18);   const float* p2_b = in(19);
  const float* p3_w = in(20);   const float* p3_b = in(21);
  const float* lin1_w = in(22); const float* lin1_b = in(23);
  const float* lin2_w = in(24); const float* lin2_b = in(25);
  const float* lin3_w = in(26); const float* lin3_b = in(27);
  const float* lin4_w = in(28); const float* lin4_b = in(29);
  const float* lin5_w = in(30); const float* lin5_b = in(31);
  const float* lin6_w = in(32); const float* lin6_b = in(33);

  float* out = (float*)d_out;
  float* out_probs = out;                      // 128*2
  float* out_dec1  = out_probs + 256;          // 4992*39
  float* out_dec2  = out_dec1 + 4992 * 39;
  float* out_dec3  = out_dec2 + 4992 * 39;
  float* out_gt1   = out_dec3 + 4992 * 39;     // 4096
  float* out_pred1 = out_gt1 + 4096;           // 4096
  float* out_gt2   = out_pred1 + 4096;         // 3328
  float* out_pred2 = out_gt2 + 3328;
  float* out_gt3   = out_pred2 + 3328;         // 2688
  float* out_pred3 = out_gt3 + 2688;

  char* base = (char*)d_ws;
  size_t off = 0;
  auto allocf = [&](size_t n) -> float* {
    float* p = (float*)(base + off);
    off += ((n * sizeof(float) + 255) & ~(size_t)255);
    return p;
  };
  auto alloci = [&](size_t n) -> int* {
    int* p = (int*)(base + off);
    off += ((n * sizeof(int) + 255) & ~(size_t)255);
    return p;
  };
  auto allocs = [&](size_t n) -> short* {
    short* p = (short*)(base + off);
    off += ((n * sizeof(short) + 255) & ~(size_t)255);
    return p;
  };

  float* wcat1 = allocf(39 * 512);
  float* wcat2 = allocf(256 * 512);
  float* wcat3 = allocf(256 * 512);
  short* wcat2t_h = allocs(512 * 256); short* wcat2t_l = allocs(512 * 256);
  short* wcat3t_h = allocs(512 * 256); short* wcat3t_l = allocs(512 * 256);
  short* wcat6t_h = allocs(78 * 256);  short* wcat6t_l = allocs(78 * 256);
  short* lin4t_h  = allocs(256 * 256); short* lin4t_l  = allocs(256 * 256);
  short* lin5t_h  = allocs(128 * 256); short* lin5t_l  = allocs(128 * 256);
  float* deg   = allocf(4992);
  float* xdeg  = allocf(4992);
  int*   idxb  = alloci(4992 * KNN_);
  float* AB    = allocf((size_t)4992 * 512);
  float* t1    = allocf((size_t)4992 * 256);
  float* t2    = allocf((size_t)4992 * 256);
  float* hbuf  = allocf((size_t)4992 * 256);
  float* xp    = allocf((size_t)4096 * 256);
  size_t ms0 = off;                             // contiguous memset region start
  float* xout  = allocf((size_t)4992 * 256);
  short* xout_h = allocs((size_t)4992 * 256);
  short* xout_l = allocs((size_t)4992 * 256);
  size_t msz = off - ms0;                       // one memset covers xout + both bf16 copies
  short* t1_h   = allocs((size_t)4992 * 256); short* t1_l   = allocs((size_t)4992 * 256);
  short* t2_h   = allocs((size_t)4992 * 256); short* t2_l   = allocs((size_t)4992 * 256);
  float* adj1  = allocf(128 * 32 * 32);
  float* adj2  = allocf(128 * 26 * 26);
  float* stats = allocf(512);
  int* perm1 = alloci(4096); int* perm2 = alloci(3328); int* perm3 = alloci(2688);
  float* z  = allocf(128 * 512);
  float* z1 = allocf(128 * 256);
  float* z2 = allocf(128 * 128);
  float* logits = allocf(256);
  if (off > ws_size) return;

  // fp32 trunk edge conv (feeds top-k; exact)
  auto edge_conv = [&](const float* xin, int n, int F, const float* wcat, const float* bias,
                       int Hout, float* outbuf) {
    int M = B_ * n;
    knn_direct_kernel<<<cdiv(M * 64, 256), 256, 0, stream>>>(xin, n, F, M, idxb);
    dim3 gg(cdiv(2 * Hout, BN), cdiv(M, BM));
    gemm_kernel<<<gg, 256, 0, stream>>>(xin, wcat, nullptr, AB, M, 2 * Hout, F, 0);
    edge_agg_kernel<<<cdiv(M * Hout, 256), 256, 0, stream>>>(AB, bias, idxb, n, Hout, 0, outbuf, nullptr, nullptr);
  };
  // split-bf16 decoder edge conv
  auto edge_conv_bf = [&](const float* xin, const short* xh, const short* xl,
                          const short* wth, const short* wtl,
                          const float* bias, int Hout, int act,
                          float* outbuf, short* outh, short* outl) {
    int M = 4992, F = 256;
    knn_direct_kernel<<<cdiv(M * 64, 256), 256, 0, stream>>>(xin, N_, F, M, idxb);
    dim3 gg(cdiv(2 * Hout, 128), cdiv(M, 128));
    mfma_gemm_split_kernel<<<gg, 256, 0, stream>>>(xh, xl, wth, wtl, nullptr, AB, nullptr, nullptr,
                                                   M, 2 * Hout, F, 0);
    edge_agg_kernel<<<cdiv(M * Hout, 256), 256, 0, stream>>>(AB, bias, idxb, N_, Hout, act, outbuf, outh, outl);
  };
  auto decoder = [&](const float* xin, const short* xh, const short* xl, float* decout) {
    edge_conv_bf(xin, xh, xl, wcat3t_h, wcat3t_l, b_mlp3, H_, 2, t1, t1_h, t1_l);
    edge_conv_bf(t1, t1_h, t1_l, wcat2t_h, wcat2t_l, b_mlp2, H_, 2, t2, t2_h, t2_l);
    edge_conv_bf(t2, t2_h, t2_l, wcat6t_h, wcat6t_l, b_mlp6, N_, 0, decout, nullptr, nullptr);
  };

  // ---- one-shot prep ----
  prep_kernel<<<dim3(512, 7), 256, 0, stream>>>(
      w_mlp1, w_mlp2, w_mlp3, w_mlp6, lin4_w, lin5_w, adj,
      wcat1, wcat2, wcat3,
      wcat2t_h, wcat2t_l, wcat3t_h, wcat3t_l, wcat6t_h, wcat6t_l,
      lin4t_h, lin4t_l, lin5t_h, lin5t_l, deg);

  // ---- level 1 ----
  edge_conv(x, N_, N_, wcat1, b_mlp1, H_, t1);
  bn_stats_kernel<<<H_, 256, 0, stream>>>(t1, 4992, stats);
  bn_apply_kernel<<<cdiv(4992 * 256, 256), 256, 0, stream>>>(t1, stats, bn1_g, bn1_b, 4992, hbuf);
  sag_kernel<<<B_, 256, 0, stream>>>(hbuf, adj, N_, K1_, p1_w, p1_b, perm1, xp, adj1);
  hipMemsetAsync(xout, 0, msz, stream);
  scatter_kernel<<<cdiv(4096 * 256, 256), 256, 0, stream>>>(xp, perm1, nullptr, 4096, xout, xout_h, xout_l);
  {
    dim3 g4(2, 39);
    mfma_gemm_split_kernel<<<g4, 256, 0, stream>>>(xout_h, xout_l, lin4t_h, lin4t_l, lin4_b,
                                                   t1, t1_h, t1_l, 4992, 256, 256, 1);
    dim3 g5(1, 39);
    mfma_gemm_split_kernel<<<g5, 256, 0, stream>>>(t1_h, t1_l, lin5t_h, lin5t_l, lin5_b,
                                                   t2, nullptr, nullptr, 4992, 128, 256, 1);
  }
  rowdot_kernel<<<cdiv(4992 * 64, 256), 256, 0, stream>>>(t2, lin6_w, 4992, 128, lin6_b, 1, xdeg);
  gtpred_kernel<<<cdiv(4096, 256), 256, 0, stream>>>(deg, xdeg, perm1, 4096, out_gt1, out_pred1);
  readout_kernel<<<cdiv(128 * 256, 256), 256, 0, stream>>>(xp, K1_, 0, z);
  decoder(xout, xout_h, xout_l, out_dec1);

  // ---- level 2 ----
  edge_conv(xp, K1_, H_, wcat2, b_mlp2, H_, t1);
  bn_stats_kernel<<<H_, 256, 0, stream>>>(t1, 4096, stats);
  bn_apply_kernel<<<cdiv(4096 * 256, 256), 256, 0, stream>>>(t1, stats, bn2_g, bn2_b, 4096, hbuf);
  sag_kernel<<<B_, 256, 0, stream>>>(hbuf, adj1, K1_, K2_, p2_w, p2_b, perm2, xp, adj2);
  hipMemsetAsync(xout, 0, msz, stream);
  scatter_kernel<<<cdiv(3328 * 256, 256), 256, 0, stream>>>(xp, perm1, perm2, 3328, xout, xout_h, xout_l);
  gtpred_kernel<<<cdiv(3328, 256), 256, 0, stream>>>(deg, xdeg, perm2, 3328, out_gt2, out_pred2);
  readout_kernel<<<cdiv(128 * 256, 256), 256, 0, stream>>>(xp, K2_, 1, z);
  decoder(xout, xout_h, xout_l, out_dec2);

  // ---- level 3 ----
  edge_conv(xp, K2_, H_, wcat3, b_mlp3, H_, t1);
  bn_stats_kernel<<<H_, 256, 0, stream>>>(t1, 3328, stats);
  bn_apply_kernel<<<cdiv(3328 * 256, 256), 256, 0, stream>>>(t1, stats, bn3_g, bn3_b, 3328, hbuf);
  sag_kernel<<<B_, 256, 0, stream>>>(hbuf, adj2, K2_, K3_, p3_w, p3_b, perm3, xp, nullptr);
  hipMemsetAsync(xout, 0, msz, stream);
  scatter_kernel<<<cdiv(2688 * 256, 256), 256, 0, stream>>>(xp, perm2, perm3, 2688, xout, xout_h, xout_l);
  gtpred_kernel<<<cdiv(2688, 256), 256, 0, stream>>>(deg, xdeg, perm3, 2688, out_gt3, out_pred3);
  readout_kernel<<<cdiv(128 * 256, 256), 256, 0, stream>>>(xp, K3_, 1, z);
  decoder(xout, xout_h, xout_l, out_dec3);

  // ---- classifier head (thin: M=128) ----
  rowgemm_kernel<<<128, 256, 0, stream>>>(z, lin1_w, lin1_b, z1, 256, 512, 1);
  rowgemm_kernel<<<128, 256, 0, stream>>>(z1, lin2_w, lin2_b, z2, 128, 256, 1);
  wavedot_gemm_kernel<<<cdiv(128 * 2 * 64, 256), 256, 0, stream>>>(z2, lin3_w, lin3_b, logits, 128, 2, 128, 0);
  softmax2_kernel<<<1, 128, 0, stream>>>(logits, out_probs);
}